// Round 4
// baseline (1027.065 us; speedup 1.0000x reference)
//
#include <hip/hip_runtime.h>
#include <math.h>

#define NSTEPS 3000
#define NWALK  1048576
#define BLOCK  256
#define NBD    (NWALK / BLOCK)   // 4096 dense blocks: one slot per lane
#define NDENSE 3                 // dense rounds cover t in [0, 192), 64 steps each
#define CHUNK  64
#define NBT    4096              // tail grid: 16384 waves (~9 walkers/wave @150k)
#define NKEYS  3072

// Ping-pong survivor lists (i, p-bits), per-round counts, precomputed keys.
__device__ uint2    g_list[2][NWALK];
__device__ uint32_t g_cnt[16];
__device__ uint2    g_keys[NKEYS];

// Threefry-2x32, 20 rounds, exactly JAX's schedule.
__device__ __forceinline__ void tf2x32(uint32_t k0, uint32_t k1,
                                       uint32_t x0, uint32_t x1,
                                       uint32_t& o0, uint32_t& o1) {
  uint32_t ks2 = k0 ^ k1 ^ 0x1BD11BDAu;
  x0 += k0; x1 += k1;
#define TFR(r) { x0 += x1; x1 = (x1 << r) | (x1 >> (32 - r)); x1 ^= x0; }
  TFR(13) TFR(15) TFR(26) TFR(6)
  x0 += k1;  x1 += ks2 + 1u;
  TFR(17) TFR(29) TFR(16) TFR(24)
  x0 += ks2; x1 += k0 + 2u;
  TFR(13) TFR(15) TFR(26) TFR(6)
  x0 += k0;  x1 += k1 + 3u;
  TFR(17) TFR(29) TFR(16) TFR(24)
  x0 += k1;  x1 += ks2 + 4u;
  TFR(13) TFR(15) TFR(26) TFR(6)
  x0 += ks2; x1 += k0 + 5u;
#undef TFR
  o0 = x0; o1 = x1;
}

// init: per-step folded split keys (counter (0,t), key (0,0)) + zero counts.
__global__ void init_kernel() {   // <<<NKEYS/256, 256>>>
  int t = blockIdx.x * 256 + threadIdx.x;
  uint32_t a, b;
  tf2x32(0u, 0u, 0u, (uint32_t)t, a, b);
  g_keys[t] = make_uint2(a, b);
  if (blockIdx.x == 0 && threadIdx.x < 16) g_cnt[threadIdx.x] = 0u;
}

// XLA CPU's log.f32 (Cephes/Eigen-3.3 plog), strict f32 mul/add, no FMA.
// Bit-exact vs reference (verified: absmax 0.094 << 0.259).
__device__ __forceinline__ float xla_cpu_log_f32(float s) {
  uint32_t bits = __float_as_uint(s);
  int emm0 = (int)(bits >> 23) - 0x7f;
  float e = __fadd_rn((float)emm0, 1.0f);
  float m = __uint_as_float((bits & 0x007fffffu) | 0x3f000000u);
  bool mlt = m < 0.70710677f;
  float tmp = mlt ? m : 0.0f;
  float x = __fsub_rn(m, 1.0f);
  e = __fsub_rn(e, mlt ? 1.0f : 0.0f);
  x = __fadd_rn(x, tmp);
  float x2 = __fmul_rn(x, x);
  float x3 = __fmul_rn(x2, x);
  float y, y1, y2;
  y  = __fadd_rn(__fmul_rn(7.0376836292e-2f,  x), -1.1514610310e-1f);
  y1 = __fadd_rn(__fmul_rn(-1.2420140846e-1f, x),  1.4249322787e-1f);
  y2 = __fadd_rn(__fmul_rn(2.0000714765e-1f,  x), -2.4999993993e-1f);
  y  = __fadd_rn(__fmul_rn(y,  x),  1.1676998740e-1f);
  y1 = __fadd_rn(__fmul_rn(y1, x), -1.6668057665e-1f);
  y2 = __fadd_rn(__fmul_rn(y2, x),  3.3333331174e-1f);
  y  = __fadd_rn(__fmul_rn(y, x3), y1);
  y  = __fadd_rn(__fmul_rn(y, x3), y2);
  y  = __fmul_rn(y, x3);
  y1 = __fmul_rn(e, -2.12194440e-4f);
  tmp = __fmul_rn(x2, 0.5f);
  y  = __fadd_rn(y, y1);
  x  = __fsub_rn(x, tmp);
  y2 = __fmul_rn(e, 0.693359375f);
  x  = __fadd_rn(x, y);
  x  = __fadd_rn(x, y2);
  return x;
}

// XLA EmitErfInv f32 (Giles): w = -log((1-x)*(1+x)), branch at w<5.
__device__ __forceinline__ float xla_erfinv_f32(float x) {
  float s = __fmul_rn(__fsub_rn(1.0f, x), __fadd_rn(1.0f, x));
  float w = -xla_cpu_log_f32(s);
  float p;
  if (w < 5.0f) {
    float v = __fsub_rn(w, 2.5f);
    p = 2.81022636e-08f;
    p = __fadd_rn(__fmul_rn(p, v), 3.43273939e-07f);
    p = __fadd_rn(__fmul_rn(p, v), -3.5233877e-06f);
    p = __fadd_rn(__fmul_rn(p, v), -4.39150654e-06f);
    p = __fadd_rn(__fmul_rn(p, v), 0.00021858087f);
    p = __fadd_rn(__fmul_rn(p, v), -0.00125372503f);
    p = __fadd_rn(__fmul_rn(p, v), -0.00417768164f);
    p = __fadd_rn(__fmul_rn(p, v), 0.246640727f);
    p = __fadd_rn(__fmul_rn(p, v), 1.50140941f);
  } else {
    float v = __fsub_rn(__fsqrt_rn(w), 3.0f);
    p = -0.000200214257f;
    p = __fadd_rn(__fmul_rn(p, v), 0.000100950558f);
    p = __fadd_rn(__fmul_rn(p, v), 0.00134934322f);
    p = __fadd_rn(__fmul_rn(p, v), -0.00367342844f);
    p = __fadd_rn(__fmul_rn(p, v), 0.00573950773f);
    p = __fadd_rn(__fmul_rn(p, v), -0.0076224613f);
    p = __fadd_rn(__fmul_rn(p, v), 0.00943887047f);
    p = __fadd_rn(__fmul_rn(p, v), 1.00167406f);
    p = __fadd_rn(__fmul_rn(p, v), 2.83297682f);
  }
  return __fmul_rn(p, x);
}

__device__ __forceinline__ float normal_from_bits(uint32_t bits) {
  const float MINVAL = __uint_as_float(0xBF7FFFFFu);   // nextafter(-1,0)
  float f = __uint_as_float((bits >> 9) | 0x3F800000u) - 1.0f;
  float u = __fadd_rn(__fmul_rn(f, 2.0f), MINVAL);
  u = fmaxf(MINVAL, u);
  const float SQRT2 = __uint_as_float(0x3FB504F3u);
  return __fmul_rn(SQRT2, xla_erfinv_f32(u));
}

// Dense round: proven shape (LDS keys, straight 64-step predicated loop, full
// unroll -> cross-step ILP; NO per-step ballots/breaks/barriers). Per-BLOCK
// aggregated atomic (R3: fixed the 16384-wave same-line atomic drain).
// R4: only rounds 0-2 remain dense — at <500 blocks a round is latency-floor
// bound (~25-30us regardless of work), so survivors at t=192 (~150k) go to
// the tail kernel, which has no per-round floor. Handover step is bit-free:
// tail performs the identical op sequence per (t,i).
template<int R>
__device__ __forceinline__
void ddm_round_body(const float* __restrict__ sv_p, const float* __restrict__ rate_p,
                    const float* __restrict__ ndt_p, const float* __restrict__ thr_p,
                    const float* __restrict__ noise_p, const float* __restrict__ dt_p,
                    const int* __restrict__ nw_p, float* __restrict__ out) {
  constexpr int t0 = R * CHUNK;
  int nw = *nw_p;
  uint32_t count = (R == 0) ? (uint32_t)nw : g_cnt[R];
  if (blockIdx.x * BLOCK >= count) return;     // block-uniform: no barriers yet

  __shared__ uint2    skeys[CHUNK];
  __shared__ uint32_t s_woff[BLOCK / 64];
  __shared__ uint32_t s_base;
  if (threadIdx.x < CHUNK) {
    uint32_t a, b;
    tf2x32(0u, 0u, 0u, (uint32_t)(t0 + threadIdx.x), a, b);
    skeys[threadIdx.x] = make_uint2(a, b);
  }
  __syncthreads();

  uint32_t slot = blockIdx.x * BLOCK + threadIdx.x;
  bool alive = slot < count;                   // no wave early-return: barriers below
  float sv = *sv_p, rate = *rate_p, ndt = *ndt_p, thr = *thr_p,
        noise = *noise_p, dt = *dt_p;
  float rate_dt = __fmul_rn(rate, dt);
  float sqrt_dt = __fsqrt_rn(dt);
  int lane = threadIdx.x & 63;
  int wv = threadIdx.x >> 6;

  int i = 0; float p = 0.0f;
  if (alive) {
    if (R == 0) { i = (int)slot; p = __fadd_rn(0.0f, sv); }
    else { uint2 e = g_list[R & 1][slot]; i = (int)e.x; p = __uint_as_float(e.y); }
  }

  for (int s = 0; s < CHUNK; ++s) {
    if (alive) {                               // dead waves: execz skip, ~free
      uint2 k = skeys[s];                      // uniform s: broadcast, no conflicts
      uint32_t b1, b2;
      tf2x32(k.x, k.y, 0u, (uint32_t)i, b1, b2);
      float z = normal_from_bits(b1 ^ b2);
      p = __fadd_rn(p, __fmul_rn(__fadd_rn(rate_dt, __fmul_rn(noise, z)), sqrt_dt));
      if (!(fabsf(p) < thr)) {
        float rts = (float)(t0 + s + 1);       // exact int == accumulated +1.0f
        out[i] = __fadd_rn(ndt, __fmul_rn(rts, dt));
        out[nw + i] = (p <= -thr) ? 0.0f : 1.0f;
        alive = false;
      }
    }
  }

  // ---- per-block aggregated compaction: ONE atomic per block ----
  uint64_t m = __ballot(alive);
  if (lane == 0) s_woff[wv] = (uint32_t)__popcll((unsigned long long)m);
  __syncthreads();
  if (threadIdx.x == 0) {
    uint32_t tot = 0;
    #pragma unroll
    for (int w = 0; w < BLOCK / 64; ++w) {
      uint32_t c = s_woff[w]; s_woff[w] = tot; tot += c;   // exclusive prefix
    }
    s_base = tot ? atomicAdd(&g_cnt[R + 1], tot) : 0u;
  }
  __syncthreads();
  if (alive) {
    uint32_t pos = s_base + s_woff[wv] +
                   (uint32_t)__popcll((unsigned long long)(m & ((1ull << lane) - 1ull)));
    g_list[(R + 1) & 1][pos] = make_uint2((uint32_t)i, __float_as_uint(p));
  }
}

// Distinct kernel names per round so rocprof top-k decomposes the timeline.
#define ARGS (const float* __restrict__ sv, const float* __restrict__ rate,   \
              const float* __restrict__ ndt, const float* __restrict__ thr,   \
              const float* __restrict__ noise, const float* __restrict__ dt,  \
              const int* __restrict__ nw, float* __restrict__ out)
#define DEFROUND(NAME, R)                                                     \
  __global__ __launch_bounds__(BLOCK) void NAME ARGS {                        \
    ddm_round_body<R>(sv, rate, ndt, thr, noise, dt, nw, out);                \
  }
DEFROUND(ddm_r0, 0)   DEFROUND(ddm_r1, 1)   DEFROUND(ddm_r2, 2)
#undef DEFROUND
#undef ARGS

// Tail: ONE WALKER PER WAVE. z_t is counter-based (depends only on (t,i)), so
// 64 lanes compute q_{t..t+63} in parallel (bit-identical op sequence), then a
// wave-uniform serial scan (exact fadd order) advances the walker 64 steps.
// No per-round latency floor; absorbs everything past t=192 (~150k walkers,
// mean remaining life ~90 steps, longest ~1100 -> ~17 iters).
__global__ __launch_bounds__(BLOCK)
void ddm_tail(const float* __restrict__ sv_p, const float* __restrict__ rate_p,
              const float* __restrict__ ndt_p, const float* __restrict__ thr_p,
              const float* __restrict__ noise_p, const float* __restrict__ dt_p,
              const int* __restrict__ nw_p, float* __restrict__ out,
              int round, int t0) {
  int nw = *nw_p;
  float rate = *rate_p, ndt = *ndt_p, thr = *thr_p,
        noise = *noise_p, dt = *dt_p;
  float rate_dt = __fmul_rn(rate, dt);
  float sqrt_dt = __fsqrt_rn(dt);

  int lane = threadIdx.x & 63;
  uint32_t wave = blockIdx.x * (BLOCK / 64) + (threadIdx.x >> 6);
  uint32_t nwaves = gridDim.x * (BLOCK / 64);
  uint32_t count = g_cnt[round];

  for (uint32_t k = wave; k < count; k += nwaves) {
    uint2 e = g_list[round & 1][k];
    int i = (int)e.x;
    float p = __uint_as_float(e.y);        // wave-uniform from here on
    int t = t0;
    int rts_i = NSTEPS;
    bool done = false;
    while (!done) {
      int valid = NSTEPS - t; if (valid > 64) valid = 64;
      int tl = t + (lane < valid ? lane : valid - 1);
      uint2 kk = g_keys[tl];               // coalesced 8B, L2-resident
      uint32_t b1, b2;
      tf2x32(kk.x, kk.y, 0u, (uint32_t)i, b1, b2);
      float z = normal_from_bits(b1 ^ b2);
      float q = __fmul_rn(__fadd_rn(rate_dt, __fmul_rn(noise, z)), sqrt_dt);
      for (int j = 0; j < valid; ++j) {    // exact sequential scan
        float qj = __shfl(q, j);
        p = __fadd_rn(p, qj);
        if (!(fabsf(p) < thr)) { rts_i = t + j + 1; done = true; break; }
      }
      if (!done) {
        t += valid;
        if (t >= NSTEPS) done = true;      // ran out the clock: rts = 3000
      }
    }
    if (lane == 0) {
      out[i] = __fadd_rn(ndt, __fmul_rn((float)rts_i, dt));
      out[nw + i] = (p <= -thr) ? 0.0f : 1.0f;
    }
  }
}

extern "C" void kernel_launch(void* const* d_in, const int* in_sizes, int n_in,
                              void* d_out, int out_size, void* d_ws, size_t ws_size,
                              hipStream_t stream) {
  const float* sv    = (const float*)d_in[0];
  const float* rate  = (const float*)d_in[1];
  const float* ndt   = (const float*)d_in[2];
  const float* thr   = (const float*)d_in[3];
  const float* noise = (const float*)d_in[4];
  const float* dt    = (const float*)d_in[5];
  const int*   nw    = (const int*)d_in[6];
  float* out = (float*)d_out;

  init_kernel<<<NKEYS / 256, 256, 0, stream>>>();
  ddm_r0<<<NBD, BLOCK, 0, stream>>>(sv, rate, ndt, thr, noise, dt, nw, out);
  ddm_r1<<<NBD, BLOCK, 0, stream>>>(sv, rate, ndt, thr, noise, dt, nw, out);
  ddm_r2<<<NBD, BLOCK, 0, stream>>>(sv, rate, ndt, thr, noise, dt, nw, out);
  ddm_tail<<<NBT, BLOCK, 0, stream>>>(sv, rate, ndt, thr, noise, dt, nw, out,
                                      NDENSE, NDENSE * CHUNK);
}

// Round 5
// 643.627 us; speedup vs baseline: 1.5957x; 1.5957x over previous
//
#include <hip/hip_runtime.h>
#include <math.h>

#define NSTEPS 3000
#define NWALK  1048576
#define BLOCK  256
#define NBD    (NWALK / BLOCK)   // 4096 dense blocks: one slot per lane
#define NDENSE 3                 // dense rounds cover t in [0, 192), 64 steps each
#define CHUNK  64
#define NBT    4096              // tail grid: 16384 waves (~8 walkers/wave @127k)
#define NKEYS  3072

// Ping-pong survivor lists (i, p-bits), per-round counts, precomputed keys.
__device__ uint2    g_list[2][NWALK];
__device__ uint32_t g_cnt[16];
__device__ uint2    g_keys[NKEYS];

// Threefry-2x32, 20 rounds, exactly JAX's schedule.
__device__ __forceinline__ void tf2x32(uint32_t k0, uint32_t k1,
                                       uint32_t x0, uint32_t x1,
                                       uint32_t& o0, uint32_t& o1) {
  uint32_t ks2 = k0 ^ k1 ^ 0x1BD11BDAu;
  x0 += k0; x1 += k1;
#define TFR(r) { x0 += x1; x1 = (x1 << r) | (x1 >> (32 - r)); x1 ^= x0; }
  TFR(13) TFR(15) TFR(26) TFR(6)
  x0 += k1;  x1 += ks2 + 1u;
  TFR(17) TFR(29) TFR(16) TFR(24)
  x0 += ks2; x1 += k0 + 2u;
  TFR(13) TFR(15) TFR(26) TFR(6)
  x0 += k0;  x1 += k1 + 3u;
  TFR(17) TFR(29) TFR(16) TFR(24)
  x0 += k1;  x1 += ks2 + 4u;
  TFR(13) TFR(15) TFR(26) TFR(6)
  x0 += ks2; x1 += k0 + 5u;
#undef TFR
  o0 = x0; o1 = x1;
}

// init: per-step folded split keys (counter (0,t), key (0,0)) + zero counts.
__global__ void init_kernel() {   // <<<NKEYS/256, 256>>>
  int t = blockIdx.x * 256 + threadIdx.x;
  uint32_t a, b;
  tf2x32(0u, 0u, 0u, (uint32_t)t, a, b);
  g_keys[t] = make_uint2(a, b);
  if (blockIdx.x == 0 && threadIdx.x < 16) g_cnt[threadIdx.x] = 0u;
}

// XLA CPU's log.f32 (Cephes/Eigen-3.3 plog), strict f32 mul/add, no FMA.
// Bit-exact vs reference (verified: absmax 0.094 << 0.259).
__device__ __forceinline__ float xla_cpu_log_f32(float s) {
  uint32_t bits = __float_as_uint(s);
  int emm0 = (int)(bits >> 23) - 0x7f;
  float e = __fadd_rn((float)emm0, 1.0f);
  float m = __uint_as_float((bits & 0x007fffffu) | 0x3f000000u);
  bool mlt = m < 0.70710677f;
  float tmp = mlt ? m : 0.0f;
  float x = __fsub_rn(m, 1.0f);
  e = __fsub_rn(e, mlt ? 1.0f : 0.0f);
  x = __fadd_rn(x, tmp);
  float x2 = __fmul_rn(x, x);
  float x3 = __fmul_rn(x2, x);
  float y, y1, y2;
  y  = __fadd_rn(__fmul_rn(7.0376836292e-2f,  x), -1.1514610310e-1f);
  y1 = __fadd_rn(__fmul_rn(-1.2420140846e-1f, x),  1.4249322787e-1f);
  y2 = __fadd_rn(__fmul_rn(2.0000714765e-1f,  x), -2.4999993993e-1f);
  y  = __fadd_rn(__fmul_rn(y,  x),  1.1676998740e-1f);
  y1 = __fadd_rn(__fmul_rn(y1, x), -1.6668057665e-1f);
  y2 = __fadd_rn(__fmul_rn(y2, x),  3.3333331174e-1f);
  y  = __fadd_rn(__fmul_rn(y, x3), y1);
  y  = __fadd_rn(__fmul_rn(y, x3), y2);
  y  = __fmul_rn(y, x3);
  y1 = __fmul_rn(e, -2.12194440e-4f);
  tmp = __fmul_rn(x2, 0.5f);
  y  = __fadd_rn(y, y1);
  x  = __fsub_rn(x, tmp);
  y2 = __fmul_rn(e, 0.693359375f);
  x  = __fadd_rn(x, y);
  x  = __fadd_rn(x, y2);
  return x;
}

// XLA EmitErfInv f32 (Giles): w = -log((1-x)*(1+x)), branch at w<5.
__device__ __forceinline__ float xla_erfinv_f32(float x) {
  float s = __fmul_rn(__fsub_rn(1.0f, x), __fadd_rn(1.0f, x));
  float w = -xla_cpu_log_f32(s);
  float p;
  if (w < 5.0f) {
    float v = __fsub_rn(w, 2.5f);
    p = 2.81022636e-08f;
    p = __fadd_rn(__fmul_rn(p, v), 3.43273939e-07f);
    p = __fadd_rn(__fmul_rn(p, v), -3.5233877e-06f);
    p = __fadd_rn(__fmul_rn(p, v), -4.39150654e-06f);
    p = __fadd_rn(__fmul_rn(p, v), 0.00021858087f);
    p = __fadd_rn(__fmul_rn(p, v), -0.00125372503f);
    p = __fadd_rn(__fmul_rn(p, v), -0.00417768164f);
    p = __fadd_rn(__fmul_rn(p, v), 0.246640727f);
    p = __fadd_rn(__fmul_rn(p, v), 1.50140941f);
  } else {
    float v = __fsub_rn(__fsqrt_rn(w), 3.0f);
    p = -0.000200214257f;
    p = __fadd_rn(__fmul_rn(p, v), 0.000100950558f);
    p = __fadd_rn(__fmul_rn(p, v), 0.00134934322f);
    p = __fadd_rn(__fmul_rn(p, v), -0.00367342844f);
    p = __fadd_rn(__fmul_rn(p, v), 0.00573950773f);
    p = __fadd_rn(__fmul_rn(p, v), -0.0076224613f);
    p = __fadd_rn(__fmul_rn(p, v), 0.00943887047f);
    p = __fadd_rn(__fmul_rn(p, v), 1.00167406f);
    p = __fadd_rn(__fmul_rn(p, v), 2.83297682f);
  }
  return __fmul_rn(p, x);
}

__device__ __forceinline__ float normal_from_bits(uint32_t bits) {
  const float MINVAL = __uint_as_float(0xBF7FFFFFu);   // nextafter(-1,0)
  float f = __uint_as_float((bits >> 9) | 0x3F800000u) - 1.0f;
  float u = __fadd_rn(__fmul_rn(f, 2.0f), MINVAL);
  u = fmaxf(MINVAL, u);
  const float SQRT2 = __uint_as_float(0x3FB504F3u);
  return __fmul_rn(SQRT2, xla_erfinv_f32(u));
}

// Dense round: proven shape (LDS keys, straight 64-step predicated loop, full
// unroll -> cross-step ILP; NO per-step ballots/breaks/barriers). Per-BLOCK
// aggregated atomic (R3: fixed the 16384-wave same-line atomic drain).
template<int R>
__device__ __forceinline__
void ddm_round_body(const float* __restrict__ sv_p, const float* __restrict__ rate_p,
                    const float* __restrict__ ndt_p, const float* __restrict__ thr_p,
                    const float* __restrict__ noise_p, const float* __restrict__ dt_p,
                    const int* __restrict__ nw_p, float* __restrict__ out) {
  constexpr int t0 = R * CHUNK;
  int nw = *nw_p;
  uint32_t count = (R == 0) ? (uint32_t)nw : g_cnt[R];
  if (blockIdx.x * BLOCK >= count) return;     // block-uniform: no barriers yet

  __shared__ uint2    skeys[CHUNK];
  __shared__ uint32_t s_woff[BLOCK / 64];
  __shared__ uint32_t s_base;
  if (threadIdx.x < CHUNK) {
    uint32_t a, b;
    tf2x32(0u, 0u, 0u, (uint32_t)(t0 + threadIdx.x), a, b);
    skeys[threadIdx.x] = make_uint2(a, b);
  }
  __syncthreads();

  uint32_t slot = blockIdx.x * BLOCK + threadIdx.x;
  bool alive = slot < count;                   // no wave early-return: barriers below
  float sv = *sv_p, rate = *rate_p, ndt = *ndt_p, thr = *thr_p,
        noise = *noise_p, dt = *dt_p;
  float rate_dt = __fmul_rn(rate, dt);
  float sqrt_dt = __fsqrt_rn(dt);
  int lane = threadIdx.x & 63;
  int wv = threadIdx.x >> 6;

  int i = 0; float p = 0.0f;
  if (alive) {
    if (R == 0) { i = (int)slot; p = __fadd_rn(0.0f, sv); }
    else { uint2 e = g_list[R & 1][slot]; i = (int)e.x; p = __uint_as_float(e.y); }
  }

  for (int s = 0; s < CHUNK; ++s) {
    if (alive) {                               // dead waves: execz skip, ~free
      uint2 k = skeys[s];                      // uniform s: broadcast, no conflicts
      uint32_t b1, b2;
      tf2x32(k.x, k.y, 0u, (uint32_t)i, b1, b2);
      float z = normal_from_bits(b1 ^ b2);
      p = __fadd_rn(p, __fmul_rn(__fadd_rn(rate_dt, __fmul_rn(noise, z)), sqrt_dt));
      if (!(fabsf(p) < thr)) {
        float rts = (float)(t0 + s + 1);       // exact int == accumulated +1.0f
        out[i] = __fadd_rn(ndt, __fmul_rn(rts, dt));
        out[nw + i] = (p <= -thr) ? 0.0f : 1.0f;
        alive = false;
      }
    }
  }

  // ---- per-block aggregated compaction: ONE atomic per block ----
  uint64_t m = __ballot(alive);
  if (lane == 0) s_woff[wv] = (uint32_t)__popcll((unsigned long long)m);
  __syncthreads();
  if (threadIdx.x == 0) {
    uint32_t tot = 0;
    #pragma unroll
    for (int w = 0; w < BLOCK / 64; ++w) {
      uint32_t c = s_woff[w]; s_woff[w] = tot; tot += c;   // exclusive prefix
    }
    s_base = tot ? atomicAdd(&g_cnt[R + 1], tot) : 0u;
  }
  __syncthreads();
  if (alive) {
    uint32_t pos = s_base + s_woff[wv] +
                   (uint32_t)__popcll((unsigned long long)(m & ((1ull << lane) - 1ull)));
    g_list[(R + 1) & 1][pos] = make_uint2((uint32_t)i, __float_as_uint(p));
  }
}

// Distinct kernel names per round so rocprof top-k decomposes the timeline.
#define ARGS (const float* __restrict__ sv, const float* __restrict__ rate,   \
              const float* __restrict__ ndt, const float* __restrict__ thr,   \
              const float* __restrict__ noise, const float* __restrict__ dt,  \
              const int* __restrict__ nw, float* __restrict__ out)
#define DEFROUND(NAME, R)                                                     \
  __global__ __launch_bounds__(BLOCK) void NAME ARGS {                        \
    ddm_round_body<R>(sv, rate, ndt, thr, noise, dt, nw, out);                \
  }
DEFROUND(ddm_r0, 0)   DEFROUND(ddm_r1, 1)   DEFROUND(ddm_r2, 2)
#undef DEFROUND
#undef ARGS

// readlane broadcast of a float (forces v_readlane, not ds_bpermute).
__device__ __forceinline__ float rdlane_f(float v, int j) {
  return __uint_as_float((uint32_t)__builtin_amdgcn_readlane((int)__float_as_uint(v), j));
}

// Tail: ONE WALKER PER WAVE. z_t is counter-based (depends only on (t,i)):
// 64 lanes compute q_{t..t+63} in parallel (bit-identical op sequence).
// R5 fix (R4 post-mortem: serial __shfl+break scan = ds_bpermute ~40cy/step,
// 90cy/walker-step measured): branchless EXACT fold — fully-unrolled 64x
// v_readlane + fadd in strict order (identical adds, identical order), with
// off-chain running max |p_j|. Only when max>=thr (the walker's death block,
// ~once per walker) re-run the checked scan from p0 to find the exact first
// crossing + sign. Fast path ~6cy/step issue, 4cy/step dep chain.
__global__ __launch_bounds__(BLOCK)
void ddm_tail(const float* __restrict__ sv_p, const float* __restrict__ rate_p,
              const float* __restrict__ ndt_p, const float* __restrict__ thr_p,
              const float* __restrict__ noise_p, const float* __restrict__ dt_p,
              const int* __restrict__ nw_p, float* __restrict__ out,
              int round, int t0) {
  int nw = *nw_p;
  float rate = *rate_p, ndt = *ndt_p, thr = *thr_p,
        noise = *noise_p, dt = *dt_p;
  float rate_dt = __fmul_rn(rate, dt);
  float sqrt_dt = __fsqrt_rn(dt);

  int lane = threadIdx.x & 63;
  uint32_t wave = blockIdx.x * (BLOCK / 64) + (threadIdx.x >> 6);
  uint32_t nwaves = gridDim.x * (BLOCK / 64);
  uint32_t count = g_cnt[round];

  for (uint32_t k = wave; k < count; k += nwaves) {
    uint2 e = g_list[round & 1][k];
    int i = (int)e.x;
    float p = __uint_as_float(e.y);        // wave-uniform from here on
    int t = t0;
    int rts_i = NSTEPS;
    bool done = false;
    while (!done) {
      int valid = NSTEPS - t; if (valid > 64) valid = 64;
      int tl = t + (lane < valid ? lane : valid - 1);
      uint2 kk = g_keys[tl];               // coalesced 8B, L2-resident
      uint32_t b1, b2;
      tf2x32(kk.x, kk.y, 0u, (uint32_t)i, b1, b2);
      float z = normal_from_bits(b1 ^ b2);
      float q = __fmul_rn(__fadd_rn(rate_dt, __fmul_rn(noise, z)), sqrt_dt);

      if (valid == 64) {
        // ---- branchless exact fold, fully unrolled ----
        float p0 = p;
        float mx = 0.0f;
        #pragma unroll
        for (int j = 0; j < 64; ++j) {
          float qj = rdlane_f(q, j);       // v_readlane, literal lane
          p = __fadd_rn(p, qj);            // strict sequential order
          mx = fmaxf(mx, fabsf(p));        // off the dependency chain
        }
        if (mx >= thr) {
          // death block: exact re-scan (same adds, same order -> same p_j)
          p = p0;
          for (int j = 0; j < 64; ++j) {
            float qj = rdlane_f(q, j);
            p = __fadd_rn(p, qj);
            if (!(fabsf(p) < thr)) { rts_i = t + j + 1; done = true; break; }
          }
        } else {
          t += 64;
          if (t >= NSTEPS) done = true;    // ran out the clock: rts = 3000
        }
      } else {
        // rare partial final block: original checked scan
        for (int j = 0; j < valid; ++j) {
          float qj = rdlane_f(q, j);
          p = __fadd_rn(p, qj);
          if (!(fabsf(p) < thr)) { rts_i = t + j + 1; done = true; break; }
        }
        if (!done) {
          t += valid;
          if (t >= NSTEPS) done = true;
        }
      }
    }
    if (lane == 0) {
      out[i] = __fadd_rn(ndt, __fmul_rn((float)rts_i, dt));
      out[nw + i] = (p <= -thr) ? 0.0f : 1.0f;
    }
  }
}

extern "C" void kernel_launch(void* const* d_in, const int* in_sizes, int n_in,
                              void* d_out, int out_size, void* d_ws, size_t ws_size,
                              hipStream_t stream) {
  const float* sv    = (const float*)d_in[0];
  const float* rate  = (const float*)d_in[1];
  const float* ndt   = (const float*)d_in[2];
  const float* thr   = (const float*)d_in[3];
  const float* noise = (const float*)d_in[4];
  const float* dt    = (const float*)d_in[5];
  const int*   nw    = (const int*)d_in[6];
  float* out = (float*)d_out;

  init_kernel<<<NKEYS / 256, 256, 0, stream>>>();
  ddm_r0<<<NBD, BLOCK, 0, stream>>>(sv, rate, ndt, thr, noise, dt, nw, out);
  ddm_r1<<<NBD, BLOCK, 0, stream>>>(sv, rate, ndt, thr, noise, dt, nw, out);
  ddm_r2<<<NBD, BLOCK, 0, stream>>>(sv, rate, ndt, thr, noise, dt, nw, out);
  ddm_tail<<<NBT, BLOCK, 0, stream>>>(sv, rate, ndt, thr, noise, dt, nw, out,
                                      NDENSE, NDENSE * CHUNK);
}

// Round 6
// 577.703 us; speedup vs baseline: 1.7778x; 1.1141x over previous
//
#include <hip/hip_runtime.h>
#include <math.h>

#define NSTEPS 3000
#define NWALK  1048576
#define BLOCK  256
#define NBD    (NWALK / BLOCK)   // 4096 dense blocks: one slot per lane
#define NDENSE 5                 // dense rounds cover t in [0, 320), 64 steps each
#define CHUNK  64
#define NBT    4096              // tail grid: 16384 waves
#define NKEYS  3072

// Ping-pong survivor lists (i, p-bits), per-round counts, precomputed keys.
__device__ uint2    g_list[2][NWALK];
__device__ uint32_t g_cnt[16];
__device__ uint2    g_keys[NKEYS];

// Threefry-2x32, 20 rounds, exactly JAX's schedule.
__device__ __forceinline__ void tf2x32(uint32_t k0, uint32_t k1,
                                       uint32_t x0, uint32_t x1,
                                       uint32_t& o0, uint32_t& o1) {
  uint32_t ks2 = k0 ^ k1 ^ 0x1BD11BDAu;
  x0 += k0; x1 += k1;
#define TFR(r) { x0 += x1; x1 = (x1 << r) | (x1 >> (32 - r)); x1 ^= x0; }
  TFR(13) TFR(15) TFR(26) TFR(6)
  x0 += k1;  x1 += ks2 + 1u;
  TFR(17) TFR(29) TFR(16) TFR(24)
  x0 += ks2; x1 += k0 + 2u;
  TFR(13) TFR(15) TFR(26) TFR(6)
  x0 += k0;  x1 += k1 + 3u;
  TFR(17) TFR(29) TFR(16) TFR(24)
  x0 += k1;  x1 += ks2 + 4u;
  TFR(13) TFR(15) TFR(26) TFR(6)
  x0 += ks2; x1 += k0 + 5u;
#undef TFR
  o0 = x0; o1 = x1;
}

// init: per-step folded split keys (counter (0,t), key (0,0)) + zero counts.
__global__ void init_kernel() {   // <<<NKEYS/256, 256>>>
  int t = blockIdx.x * 256 + threadIdx.x;
  uint32_t a, b;
  tf2x32(0u, 0u, 0u, (uint32_t)t, a, b);
  g_keys[t] = make_uint2(a, b);
  if (blockIdx.x == 0 && threadIdx.x < 16) g_cnt[threadIdx.x] = 0u;
}

// XLA CPU's log.f32 (Cephes/Eigen-3.3 plog), strict f32 mul/add, no FMA.
// Bit-exact vs reference (verified: absmax 0.094 << 0.259).
__device__ __forceinline__ float xla_cpu_log_f32(float s) {
  uint32_t bits = __float_as_uint(s);
  int emm0 = (int)(bits >> 23) - 0x7f;
  float e = __fadd_rn((float)emm0, 1.0f);
  float m = __uint_as_float((bits & 0x007fffffu) | 0x3f000000u);
  bool mlt = m < 0.70710677f;
  float tmp = mlt ? m : 0.0f;
  float x = __fsub_rn(m, 1.0f);
  e = __fsub_rn(e, mlt ? 1.0f : 0.0f);
  x = __fadd_rn(x, tmp);
  float x2 = __fmul_rn(x, x);
  float x3 = __fmul_rn(x2, x);
  float y, y1, y2;
  y  = __fadd_rn(__fmul_rn(7.0376836292e-2f,  x), -1.1514610310e-1f);
  y1 = __fadd_rn(__fmul_rn(-1.2420140846e-1f, x),  1.4249322787e-1f);
  y2 = __fadd_rn(__fmul_rn(2.0000714765e-1f,  x), -2.4999993993e-1f);
  y  = __fadd_rn(__fmul_rn(y,  x),  1.1676998740e-1f);
  y1 = __fadd_rn(__fmul_rn(y1, x), -1.6668057665e-1f);
  y2 = __fadd_rn(__fmul_rn(y2, x),  3.3333331174e-1f);
  y  = __fadd_rn(__fmul_rn(y, x3), y1);
  y  = __fadd_rn(__fmul_rn(y, x3), y2);
  y  = __fmul_rn(y, x3);
  y1 = __fmul_rn(e, -2.12194440e-4f);
  tmp = __fmul_rn(x2, 0.5f);
  y  = __fadd_rn(y, y1);
  x  = __fsub_rn(x, tmp);
  y2 = __fmul_rn(e, 0.693359375f);
  x  = __fadd_rn(x, y);
  x  = __fadd_rn(x, y2);
  return x;
}

// XLA EmitErfInv f32 (Giles): w = -log((1-x)*(1+x)), branch at w<5.
__device__ __forceinline__ float xla_erfinv_f32(float x) {
  float s = __fmul_rn(__fsub_rn(1.0f, x), __fadd_rn(1.0f, x));
  float w = -xla_cpu_log_f32(s);
  float p;
  if (w < 5.0f) {
    float v = __fsub_rn(w, 2.5f);
    p = 2.81022636e-08f;
    p = __fadd_rn(__fmul_rn(p, v), 3.43273939e-07f);
    p = __fadd_rn(__fmul_rn(p, v), -3.5233877e-06f);
    p = __fadd_rn(__fmul_rn(p, v), -4.39150654e-06f);
    p = __fadd_rn(__fmul_rn(p, v), 0.00021858087f);
    p = __fadd_rn(__fmul_rn(p, v), -0.00125372503f);
    p = __fadd_rn(__fmul_rn(p, v), -0.00417768164f);
    p = __fadd_rn(__fmul_rn(p, v), 0.246640727f);
    p = __fadd_rn(__fmul_rn(p, v), 1.50140941f);
  } else {
    float v = __fsub_rn(__fsqrt_rn(w), 3.0f);
    p = -0.000200214257f;
    p = __fadd_rn(__fmul_rn(p, v), 0.000100950558f);
    p = __fadd_rn(__fmul_rn(p, v), 0.00134934322f);
    p = __fadd_rn(__fmul_rn(p, v), -0.00367342844f);
    p = __fadd_rn(__fmul_rn(p, v), 0.00573950773f);
    p = __fadd_rn(__fmul_rn(p, v), -0.0076224613f);
    p = __fadd_rn(__fmul_rn(p, v), 0.00943887047f);
    p = __fadd_rn(__fmul_rn(p, v), 1.00167406f);
    p = __fadd_rn(__fmul_rn(p, v), 2.83297682f);
  }
  return __fmul_rn(p, x);
}

__device__ __forceinline__ float normal_from_bits(uint32_t bits) {
  const float MINVAL = __uint_as_float(0xBF7FFFFFu);   // nextafter(-1,0)
  float f = __uint_as_float((bits >> 9) | 0x3F800000u) - 1.0f;
  float u = __fadd_rn(__fmul_rn(f, 2.0f), MINVAL);
  u = fmaxf(MINVAL, u);
  const float SQRT2 = __uint_as_float(0x3FB504F3u);
  return __fmul_rn(SQRT2, xla_erfinv_f32(u));
}

// Dense round: proven shape (LDS keys, straight 64-step predicated loop, full
// unroll -> cross-step ILP; NO per-step ballots/breaks/barriers). Per-BLOCK
// aggregated atomic (R3: fixed the 16384-wave same-line atomic drain).
// R6: dense through t=320. Dense costs ~2.3 instr/walker-step vs tail's ~6.3;
// dense is the right regime down to ~70k survivors (latency floor ~15-20us).
template<int R>
__device__ __forceinline__
void ddm_round_body(const float* __restrict__ sv_p, const float* __restrict__ rate_p,
                    const float* __restrict__ ndt_p, const float* __restrict__ thr_p,
                    const float* __restrict__ noise_p, const float* __restrict__ dt_p,
                    const int* __restrict__ nw_p, float* __restrict__ out) {
  constexpr int t0 = R * CHUNK;
  int nw = *nw_p;
  uint32_t count = (R == 0) ? (uint32_t)nw : g_cnt[R];
  if (blockIdx.x * BLOCK >= count) return;     // block-uniform: no barriers yet

  __shared__ uint2    skeys[CHUNK];
  __shared__ uint32_t s_woff[BLOCK / 64];
  __shared__ uint32_t s_base;
  if (threadIdx.x < CHUNK) {
    uint32_t a, b;
    tf2x32(0u, 0u, 0u, (uint32_t)(t0 + threadIdx.x), a, b);
    skeys[threadIdx.x] = make_uint2(a, b);
  }
  __syncthreads();

  uint32_t slot = blockIdx.x * BLOCK + threadIdx.x;
  bool alive = slot < count;                   // no wave early-return: barriers below
  float sv = *sv_p, rate = *rate_p, ndt = *ndt_p, thr = *thr_p,
        noise = *noise_p, dt = *dt_p;
  float rate_dt = __fmul_rn(rate, dt);
  float sqrt_dt = __fsqrt_rn(dt);
  int lane = threadIdx.x & 63;
  int wv = threadIdx.x >> 6;

  int i = 0; float p = 0.0f;
  if (alive) {
    if (R == 0) { i = (int)slot; p = __fadd_rn(0.0f, sv); }
    else { uint2 e = g_list[R & 1][slot]; i = (int)e.x; p = __uint_as_float(e.y); }
  }

  for (int s = 0; s < CHUNK; ++s) {
    if (alive) {                               // dead waves: execz skip, ~free
      uint2 k = skeys[s];                      // uniform s: broadcast, no conflicts
      uint32_t b1, b2;
      tf2x32(k.x, k.y, 0u, (uint32_t)i, b1, b2);
      float z = normal_from_bits(b1 ^ b2);
      p = __fadd_rn(p, __fmul_rn(__fadd_rn(rate_dt, __fmul_rn(noise, z)), sqrt_dt));
      if (!(fabsf(p) < thr)) {
        float rts = (float)(t0 + s + 1);       // exact int == accumulated +1.0f
        out[i] = __fadd_rn(ndt, __fmul_rn(rts, dt));
        out[nw + i] = (p <= -thr) ? 0.0f : 1.0f;
        alive = false;
      }
    }
  }

  // ---- per-block aggregated compaction: ONE atomic per block ----
  uint64_t m = __ballot(alive);
  if (lane == 0) s_woff[wv] = (uint32_t)__popcll((unsigned long long)m);
  __syncthreads();
  if (threadIdx.x == 0) {
    uint32_t tot = 0;
    #pragma unroll
    for (int w = 0; w < BLOCK / 64; ++w) {
      uint32_t c = s_woff[w]; s_woff[w] = tot; tot += c;   // exclusive prefix
    }
    s_base = tot ? atomicAdd(&g_cnt[R + 1], tot) : 0u;
  }
  __syncthreads();
  if (alive) {
    uint32_t pos = s_base + s_woff[wv] +
                   (uint32_t)__popcll((unsigned long long)(m & ((1ull << lane) - 1ull)));
    g_list[(R + 1) & 1][pos] = make_uint2((uint32_t)i, __float_as_uint(p));
  }
}

// Distinct kernel names per round so rocprof top-k decomposes the timeline.
#define ARGS (const float* __restrict__ sv, const float* __restrict__ rate,   \
              const float* __restrict__ ndt, const float* __restrict__ thr,   \
              const float* __restrict__ noise, const float* __restrict__ dt,  \
              const int* __restrict__ nw, float* __restrict__ out)
#define DEFROUND(NAME, R)                                                     \
  __global__ __launch_bounds__(BLOCK) void NAME ARGS {                        \
    ddm_round_body<R>(sv, rate, ndt, thr, noise, dt, nw, out);                \
  }
DEFROUND(ddm_r0, 0)   DEFROUND(ddm_r1, 1)   DEFROUND(ddm_r2, 2)
DEFROUND(ddm_r3, 3)   DEFROUND(ddm_r4, 4)
#undef DEFROUND
#undef ARGS

// readlane broadcast of a float (forces v_readlane, not ds_bpermute).
__device__ __forceinline__ float rdlane_f(float v, int j) {
  return __uint_as_float((uint32_t)__builtin_amdgcn_readlane((int)__float_as_uint(v), j));
}

// Tail: ONE WALKER PER WAVE. z_t is counter-based (depends only on (t,i)):
// 64 lanes compute q_{t..t+63} in parallel (bit-identical op sequence).
// Branchless EXACT fold (R5): fully-unrolled 64x v_readlane + fadd in strict
// order (identical adds, identical order), off-chain running max |p_j|. Only
// the death block (max>=thr, ~once per walker) re-runs the checked scan from
// p0 to find the exact first crossing + sign.
__global__ __launch_bounds__(BLOCK)
void ddm_tail(const float* __restrict__ sv_p, const float* __restrict__ rate_p,
              const float* __restrict__ ndt_p, const float* __restrict__ thr_p,
              const float* __restrict__ noise_p, const float* __restrict__ dt_p,
              const int* __restrict__ nw_p, float* __restrict__ out,
              int round, int t0) {
  int nw = *nw_p;
  float rate = *rate_p, ndt = *ndt_p, thr = *thr_p,
        noise = *noise_p, dt = *dt_p;
  float rate_dt = __fmul_rn(rate, dt);
  float sqrt_dt = __fsqrt_rn(dt);

  int lane = threadIdx.x & 63;
  uint32_t wave = blockIdx.x * (BLOCK / 64) + (threadIdx.x >> 6);
  uint32_t nwaves = gridDim.x * (BLOCK / 64);
  uint32_t count = g_cnt[round];

  for (uint32_t k = wave; k < count; k += nwaves) {
    uint2 e = g_list[round & 1][k];
    int i = (int)e.x;
    float p = __uint_as_float(e.y);        // wave-uniform from here on
    int t = t0;
    int rts_i = NSTEPS;
    bool done = false;
    while (!done) {
      int valid = NSTEPS - t; if (valid > 64) valid = 64;
      int tl = t + (lane < valid ? lane : valid - 1);
      uint2 kk = g_keys[tl];               // coalesced 8B, L2-resident
      uint32_t b1, b2;
      tf2x32(kk.x, kk.y, 0u, (uint32_t)i, b1, b2);
      float z = normal_from_bits(b1 ^ b2);
      float q = __fmul_rn(__fadd_rn(rate_dt, __fmul_rn(noise, z)), sqrt_dt);

      if (valid == 64) {
        // ---- branchless exact fold, fully unrolled ----
        float p0 = p;
        float mx = 0.0f;
        #pragma unroll
        for (int j = 0; j < 64; ++j) {
          float qj = rdlane_f(q, j);       // v_readlane, literal lane
          p = __fadd_rn(p, qj);            // strict sequential order
          mx = fmaxf(mx, fabsf(p));        // off the dependency chain
        }
        if (mx >= thr) {
          // death block: exact re-scan (same adds, same order -> same p_j)
          p = p0;
          for (int j = 0; j < 64; ++j) {
            float qj = rdlane_f(q, j);
            p = __fadd_rn(p, qj);
            if (!(fabsf(p) < thr)) { rts_i = t + j + 1; done = true; break; }
          }
        } else {
          t += 64;
          if (t >= NSTEPS) done = true;    // ran out the clock: rts = 3000
        }
      } else {
        // rare partial final block: original checked scan
        for (int j = 0; j < valid; ++j) {
          float qj = rdlane_f(q, j);
          p = __fadd_rn(p, qj);
          if (!(fabsf(p) < thr)) { rts_i = t + j + 1; done = true; break; }
        }
        if (!done) {
          t += valid;
          if (t >= NSTEPS) done = true;
        }
      }
    }
    if (lane == 0) {
      out[i] = __fadd_rn(ndt, __fmul_rn((float)rts_i, dt));
      out[nw + i] = (p <= -thr) ? 0.0f : 1.0f;
    }
  }
}

extern "C" void kernel_launch(void* const* d_in, const int* in_sizes, int n_in,
                              void* d_out, int out_size, void* d_ws, size_t ws_size,
                              hipStream_t stream) {
  const float* sv    = (const float*)d_in[0];
  const float* rate  = (const float*)d_in[1];
  const float* ndt   = (const float*)d_in[2];
  const float* thr   = (const float*)d_in[3];
  const float* noise = (const float*)d_in[4];
  const float* dt    = (const float*)d_in[5];
  const int*   nw    = (const int*)d_in[6];
  float* out = (float*)d_out;

  init_kernel<<<NKEYS / 256, 256, 0, stream>>>();
  ddm_r0<<<NBD, BLOCK, 0, stream>>>(sv, rate, ndt, thr, noise, dt, nw, out);
  ddm_r1<<<NBD, BLOCK, 0, stream>>>(sv, rate, ndt, thr, noise, dt, nw, out);
  ddm_r2<<<NBD, BLOCK, 0, stream>>>(sv, rate, ndt, thr, noise, dt, nw, out);
  ddm_r3<<<NBD, BLOCK, 0, stream>>>(sv, rate, ndt, thr, noise, dt, nw, out);
  ddm_r4<<<NBD, BLOCK, 0, stream>>>(sv, rate, ndt, thr, noise, dt, nw, out);
  ddm_tail<<<NBT, BLOCK, 0, stream>>>(sv, rate, ndt, thr, noise, dt, nw, out,
                                      NDENSE, NDENSE * CHUNK);
}

// Round 7
// 574.274 us; speedup vs baseline: 1.7885x; 1.0060x over previous
//
#include <hip/hip_runtime.h>
#include <math.h>

#define NSTEPS 3000
#define NWALK  1048576
#define BLOCK  256
#define NBD    (NWALK / BLOCK)   // 4096 dense blocks: one slot per lane
#define NDENSE 6                 // dense rounds cover t in [0, 384), 64 steps each
#define CHUNK  64
#define NBT    4096              // tail grid: 16384 waves
#define NKEYS  3072

// Ping-pong survivor lists (i, p-bits), per-round counts, precomputed keys.
__device__ uint2    g_list[2][NWALK];
__device__ uint32_t g_cnt[16];
__device__ uint2    g_keys[NKEYS];

// Threefry-2x32, 20 rounds, exactly JAX's schedule.
__device__ __forceinline__ void tf2x32(uint32_t k0, uint32_t k1,
                                       uint32_t x0, uint32_t x1,
                                       uint32_t& o0, uint32_t& o1) {
  uint32_t ks2 = k0 ^ k1 ^ 0x1BD11BDAu;
  x0 += k0; x1 += k1;
#define TFR(r) { x0 += x1; x1 = (x1 << r) | (x1 >> (32 - r)); x1 ^= x0; }
  TFR(13) TFR(15) TFR(26) TFR(6)
  x0 += k1;  x1 += ks2 + 1u;
  TFR(17) TFR(29) TFR(16) TFR(24)
  x0 += ks2; x1 += k0 + 2u;
  TFR(13) TFR(15) TFR(26) TFR(6)
  x0 += k0;  x1 += k1 + 3u;
  TFR(17) TFR(29) TFR(16) TFR(24)
  x0 += k1;  x1 += ks2 + 4u;
  TFR(13) TFR(15) TFR(26) TFR(6)
  x0 += ks2; x1 += k0 + 5u;
#undef TFR
  o0 = x0; o1 = x1;
}

// init: per-step folded split keys (counter (0,t), key (0,0)) + zero counts.
__global__ void init_kernel() {   // <<<NKEYS/256, 256>>>
  int t = blockIdx.x * 256 + threadIdx.x;
  uint32_t a, b;
  tf2x32(0u, 0u, 0u, (uint32_t)t, a, b);
  g_keys[t] = make_uint2(a, b);
  if (blockIdx.x == 0 && threadIdx.x < 16) g_cnt[threadIdx.x] = 0u;
}

// XLA CPU's log.f32 (Cephes/Eigen-3.3 plog), strict f32 mul/add, no FMA.
// Bit-exact vs reference (verified: absmax 0.094 << 0.259).
__device__ __forceinline__ float xla_cpu_log_f32(float s) {
  uint32_t bits = __float_as_uint(s);
  int emm0 = (int)(bits >> 23) - 0x7f;
  float e = __fadd_rn((float)emm0, 1.0f);
  float m = __uint_as_float((bits & 0x007fffffu) | 0x3f000000u);
  bool mlt = m < 0.70710677f;
  float tmp = mlt ? m : 0.0f;
  float x = __fsub_rn(m, 1.0f);
  e = __fsub_rn(e, mlt ? 1.0f : 0.0f);
  x = __fadd_rn(x, tmp);
  float x2 = __fmul_rn(x, x);
  float x3 = __fmul_rn(x2, x);
  float y, y1, y2;
  y  = __fadd_rn(__fmul_rn(7.0376836292e-2f,  x), -1.1514610310e-1f);
  y1 = __fadd_rn(__fmul_rn(-1.2420140846e-1f, x),  1.4249322787e-1f);
  y2 = __fadd_rn(__fmul_rn(2.0000714765e-1f,  x), -2.4999993993e-1f);
  y  = __fadd_rn(__fmul_rn(y,  x),  1.1676998740e-1f);
  y1 = __fadd_rn(__fmul_rn(y1, x), -1.6668057665e-1f);
  y2 = __fadd_rn(__fmul_rn(y2, x),  3.3333331174e-1f);
  y  = __fadd_rn(__fmul_rn(y, x3), y1);
  y  = __fadd_rn(__fmul_rn(y, x3), y2);
  y  = __fmul_rn(y, x3);
  y1 = __fmul_rn(e, -2.12194440e-4f);
  tmp = __fmul_rn(x2, 0.5f);
  y  = __fadd_rn(y, y1);
  x  = __fsub_rn(x, tmp);
  y2 = __fmul_rn(e, 0.693359375f);
  x  = __fadd_rn(x, y);
  x  = __fadd_rn(x, y2);
  return x;
}

// XLA EmitErfInv f32 (Giles): w = -log((1-x)*(1+x)), branch at w<5.
__device__ __forceinline__ float xla_erfinv_f32(float x) {
  float s = __fmul_rn(__fsub_rn(1.0f, x), __fadd_rn(1.0f, x));
  float w = -xla_cpu_log_f32(s);
  float p;
  if (w < 5.0f) {
    float v = __fsub_rn(w, 2.5f);
    p = 2.81022636e-08f;
    p = __fadd_rn(__fmul_rn(p, v), 3.43273939e-07f);
    p = __fadd_rn(__fmul_rn(p, v), -3.5233877e-06f);
    p = __fadd_rn(__fmul_rn(p, v), -4.39150654e-06f);
    p = __fadd_rn(__fmul_rn(p, v), 0.00021858087f);
    p = __fadd_rn(__fmul_rn(p, v), -0.00125372503f);
    p = __fadd_rn(__fmul_rn(p, v), -0.00417768164f);
    p = __fadd_rn(__fmul_rn(p, v), 0.246640727f);
    p = __fadd_rn(__fmul_rn(p, v), 1.50140941f);
  } else {
    float v = __fsub_rn(__fsqrt_rn(w), 3.0f);
    p = -0.000200214257f;
    p = __fadd_rn(__fmul_rn(p, v), 0.000100950558f);
    p = __fadd_rn(__fmul_rn(p, v), 0.00134934322f);
    p = __fadd_rn(__fmul_rn(p, v), -0.00367342844f);
    p = __fadd_rn(__fmul_rn(p, v), 0.00573950773f);
    p = __fadd_rn(__fmul_rn(p, v), -0.0076224613f);
    p = __fadd_rn(__fmul_rn(p, v), 0.00943887047f);
    p = __fadd_rn(__fmul_rn(p, v), 1.00167406f);
    p = __fadd_rn(__fmul_rn(p, v), 2.83297682f);
  }
  return __fmul_rn(p, x);
}

__device__ __forceinline__ float normal_from_bits(uint32_t bits) {
  const float MINVAL = __uint_as_float(0xBF7FFFFFu);   // nextafter(-1,0)
  float f = __uint_as_float((bits >> 9) | 0x3F800000u) - 1.0f;
  float u = __fadd_rn(__fmul_rn(f, 2.0f), MINVAL);
  u = fmaxf(MINVAL, u);
  const float SQRT2 = __uint_as_float(0x3FB504F3u);
  return __fmul_rn(SQRT2, xla_erfinv_f32(u));
}

// Dense round: proven shape (LDS keys, straight 64-step predicated loop, full
// unroll -> cross-step ILP; NO per-step ballots/breaks/barriers). Per-BLOCK
// aggregated atomic (R3: fixed the 16384-wave same-line atomic drain).
// R7: dense through t=384. Deep rounds are latency-floored (~17us: serial
// 64-step dep chain at <2 waves/SIMD), but r5 at ~52k still beats the tail
// doing those steps (~24us block-iters + ~6us rescans).
template<int R>
__device__ __forceinline__
void ddm_round_body(const float* __restrict__ sv_p, const float* __restrict__ rate_p,
                    const float* __restrict__ ndt_p, const float* __restrict__ thr_p,
                    const float* __restrict__ noise_p, const float* __restrict__ dt_p,
                    const int* __restrict__ nw_p, float* __restrict__ out) {
  constexpr int t0 = R * CHUNK;
  int nw = *nw_p;
  uint32_t count = (R == 0) ? (uint32_t)nw : g_cnt[R];
  if (blockIdx.x * BLOCK >= count) return;     // block-uniform: no barriers yet

  __shared__ uint2    skeys[CHUNK];
  __shared__ uint32_t s_woff[BLOCK / 64];
  __shared__ uint32_t s_base;
  if (threadIdx.x < CHUNK) {
    uint32_t a, b;
    tf2x32(0u, 0u, 0u, (uint32_t)(t0 + threadIdx.x), a, b);
    skeys[threadIdx.x] = make_uint2(a, b);
  }
  __syncthreads();

  uint32_t slot = blockIdx.x * BLOCK + threadIdx.x;
  bool alive = slot < count;                   // no wave early-return: barriers below
  float sv = *sv_p, rate = *rate_p, ndt = *ndt_p, thr = *thr_p,
        noise = *noise_p, dt = *dt_p;
  float rate_dt = __fmul_rn(rate, dt);
  float sqrt_dt = __fsqrt_rn(dt);
  int lane = threadIdx.x & 63;
  int wv = threadIdx.x >> 6;

  int i = 0; float p = 0.0f;
  if (alive) {
    if (R == 0) { i = (int)slot; p = __fadd_rn(0.0f, sv); }
    else { uint2 e = g_list[R & 1][slot]; i = (int)e.x; p = __uint_as_float(e.y); }
  }

  for (int s = 0; s < CHUNK; ++s) {
    if (alive) {                               // dead waves: execz skip, ~free
      uint2 k = skeys[s];                      // uniform s: broadcast, no conflicts
      uint32_t b1, b2;
      tf2x32(k.x, k.y, 0u, (uint32_t)i, b1, b2);
      float z = normal_from_bits(b1 ^ b2);
      p = __fadd_rn(p, __fmul_rn(__fadd_rn(rate_dt, __fmul_rn(noise, z)), sqrt_dt));
      if (!(fabsf(p) < thr)) {
        float rts = (float)(t0 + s + 1);       // exact int == accumulated +1.0f
        out[i] = __fadd_rn(ndt, __fmul_rn(rts, dt));
        out[nw + i] = (p <= -thr) ? 0.0f : 1.0f;
        alive = false;
      }
    }
  }

  // ---- per-block aggregated compaction: ONE atomic per block ----
  uint64_t m = __ballot(alive);
  if (lane == 0) s_woff[wv] = (uint32_t)__popcll((unsigned long long)m);
  __syncthreads();
  if (threadIdx.x == 0) {
    uint32_t tot = 0;
    #pragma unroll
    for (int w = 0; w < BLOCK / 64; ++w) {
      uint32_t c = s_woff[w]; s_woff[w] = tot; tot += c;   // exclusive prefix
    }
    s_base = tot ? atomicAdd(&g_cnt[R + 1], tot) : 0u;
  }
  __syncthreads();
  if (alive) {
    uint32_t pos = s_base + s_woff[wv] +
                   (uint32_t)__popcll((unsigned long long)(m & ((1ull << lane) - 1ull)));
    g_list[(R + 1) & 1][pos] = make_uint2((uint32_t)i, __float_as_uint(p));
  }
}

// Distinct kernel names per round so rocprof top-k decomposes the timeline.
#define ARGS (const float* __restrict__ sv, const float* __restrict__ rate,   \
              const float* __restrict__ ndt, const float* __restrict__ thr,   \
              const float* __restrict__ noise, const float* __restrict__ dt,  \
              const int* __restrict__ nw, float* __restrict__ out)
#define DEFROUND(NAME, R)                                                     \
  __global__ __launch_bounds__(BLOCK) void NAME ARGS {                        \
    ddm_round_body<R>(sv, rate, ndt, thr, noise, dt, nw, out);                \
  }
DEFROUND(ddm_r0, 0)   DEFROUND(ddm_r1, 1)   DEFROUND(ddm_r2, 2)
DEFROUND(ddm_r3, 3)   DEFROUND(ddm_r4, 4)   DEFROUND(ddm_r5, 5)
#undef DEFROUND
#undef ARGS

// readlane broadcast of a float (forces v_readlane, not ds_bpermute).
__device__ __forceinline__ float rdlane_f(float v, int j) {
  return __uint_as_float((uint32_t)__builtin_amdgcn_readlane((int)__float_as_uint(v), j));
}

// Tail: ONE WALKER PER WAVE. 64 lanes compute q_{t..t+63} in parallel
// (bit-identical op sequence), then a branchless EXACT fold: fully-unrolled
// 64x v_readlane + fadd in strict order, mx tracked per 16-step QUARTER
// (R7: + p snapshots at quarter boundaries). Death block (~once per walker):
// rescan only the first quarter whose mx >= thr, from its exact snapshot —
// <=16 serial steps instead of ~32 avg. Chain values identical (same adds,
// same order) -> outputs bit-identical. All branch conditions wave-uniform.
__global__ __launch_bounds__(BLOCK)
void ddm_tail(const float* __restrict__ sv_p, const float* __restrict__ rate_p,
              const float* __restrict__ ndt_p, const float* __restrict__ thr_p,
              const float* __restrict__ noise_p, const float* __restrict__ dt_p,
              const int* __restrict__ nw_p, float* __restrict__ out,
              int round, int t0) {
  int nw = *nw_p;
  float rate = *rate_p, ndt = *ndt_p, thr = *thr_p,
        noise = *noise_p, dt = *dt_p;
  float rate_dt = __fmul_rn(rate, dt);
  float sqrt_dt = __fsqrt_rn(dt);

  int lane = threadIdx.x & 63;
  uint32_t wave = blockIdx.x * (BLOCK / 64) + (threadIdx.x >> 6);
  uint32_t nwaves = gridDim.x * (BLOCK / 64);
  uint32_t count = g_cnt[round];

  for (uint32_t k = wave; k < count; k += nwaves) {
    uint2 e = g_list[round & 1][k];
    int i = (int)e.x;
    float p = __uint_as_float(e.y);        // wave-uniform from here on
    int t = t0;
    int rts_i = NSTEPS;
    bool done = false;
    while (!done) {
      int valid = NSTEPS - t; if (valid > 64) valid = 64;
      int tl = t + (lane < valid ? lane : valid - 1);
      uint2 kk = g_keys[tl];               // coalesced 8B, L2-resident
      uint32_t b1, b2;
      tf2x32(kk.x, kk.y, 0u, (uint32_t)i, b1, b2);
      float z = normal_from_bits(b1 ^ b2);
      float q = __fmul_rn(__fadd_rn(rate_dt, __fmul_rn(noise, z)), sqrt_dt);

      if (valid == 64) {
        // ---- branchless exact fold, quarter-snapshotted ----
        float s0 = p, mx0 = 0.0f, mx1 = 0.0f, mx2 = 0.0f, mx3 = 0.0f;
        #pragma unroll
        for (int j = 0; j < 16; ++j) {
          p = __fadd_rn(p, rdlane_f(q, j));  mx0 = fmaxf(mx0, fabsf(p));
        }
        float s1 = p;
        #pragma unroll
        for (int j = 16; j < 32; ++j) {
          p = __fadd_rn(p, rdlane_f(q, j));  mx1 = fmaxf(mx1, fabsf(p));
        }
        float s2 = p;
        #pragma unroll
        for (int j = 32; j < 48; ++j) {
          p = __fadd_rn(p, rdlane_f(q, j));  mx2 = fmaxf(mx2, fabsf(p));
        }
        float s3 = p;
        #pragma unroll
        for (int j = 48; j < 64; ++j) {
          p = __fadd_rn(p, rdlane_f(q, j));  mx3 = fmaxf(mx3, fabsf(p));
        }
        if (fmaxf(fmaxf(mx0, mx1), fmaxf(mx2, mx3)) >= thr) {
          // death block: first crossing lives in the FIRST quarter w/ mx>=thr
          float pr; int jb;
          if      (mx0 >= thr) { pr = s0; jb = 0;  }
          else if (mx1 >= thr) { pr = s1; jb = 16; }
          else if (mx2 >= thr) { pr = s2; jb = 32; }
          else                 { pr = s3; jb = 48; }
          for (int j = 0; j < 16; ++j) {   // exact re-scan from snapshot
            pr = __fadd_rn(pr, rdlane_f(q, jb + j));
            if (!(fabsf(pr) < thr)) {
              rts_i = t + jb + j + 1; p = pr; done = true; break;
            }
          }
        } else {
          t += 64;
          if (t >= NSTEPS) done = true;    // ran out the clock: rts = 3000
        }
      } else {
        // rare partial final block: original checked scan
        for (int j = 0; j < valid; ++j) {
          float qj = rdlane_f(q, j);
          p = __fadd_rn(p, qj);
          if (!(fabsf(p) < thr)) { rts_i = t + j + 1; done = true; break; }
        }
        if (!done) {
          t += valid;
          if (t >= NSTEPS) done = true;
        }
      }
    }
    if (lane == 0) {
      out[i] = __fadd_rn(ndt, __fmul_rn((float)rts_i, dt));
      out[nw + i] = (p <= -thr) ? 0.0f : 1.0f;
    }
  }
}

extern "C" void kernel_launch(void* const* d_in, const int* in_sizes, int n_in,
                              void* d_out, int out_size, void* d_ws, size_t ws_size,
                              hipStream_t stream) {
  const float* sv    = (const float*)d_in[0];
  const float* rate  = (const float*)d_in[1];
  const float* ndt   = (const float*)d_in[2];
  const float* thr   = (const float*)d_in[3];
  const float* noise = (const float*)d_in[4];
  const float* dt    = (const float*)d_in[5];
  const int*   nw    = (const int*)d_in[6];
  float* out = (float*)d_out;

  init_kernel<<<NKEYS / 256, 256, 0, stream>>>();
  ddm_r0<<<NBD, BLOCK, 0, stream>>>(sv, rate, ndt, thr, noise, dt, nw, out);
  ddm_r1<<<NBD, BLOCK, 0, stream>>>(sv, rate, ndt, thr, noise, dt, nw, out);
  ddm_r2<<<NBD, BLOCK, 0, stream>>>(sv, rate, ndt, thr, noise, dt, nw, out);
  ddm_r3<<<NBD, BLOCK, 0, stream>>>(sv, rate, ndt, thr, noise, dt, nw, out);
  ddm_r4<<<NBD, BLOCK, 0, stream>>>(sv, rate, ndt, thr, noise, dt, nw, out);
  ddm_r5<<<NBD, BLOCK, 0, stream>>>(sv, rate, ndt, thr, noise, dt, nw, out);
  ddm_tail<<<NBT, BLOCK, 0, stream>>>(sv, rate, ndt, thr, noise, dt, nw, out,
                                      NDENSE, NDENSE * CHUNK);
}

// Round 8
// 530.813 us; speedup vs baseline: 1.9349x; 1.0819x over previous
//
#include <hip/hip_runtime.h>
#include <math.h>

#define NSTEPS 3000
#define NWALK  1048576
#define BLOCK  256
#define NBD    (NWALK / BLOCK)   // 4096 dense blocks: one slot per lane
#define NDENSE 6                 // dense rounds cover t in [0, 384), 64 steps each
#define CHUNK  64
#define NBT    4096              // tail grid: 16384 waves
#define NKEYS  3072

// R8: FMA contraction toggle. The reference already differs from our strict
// no-FMA emulation by absmax 0.094 (ulp-level backend divergence, ZERO
// decision flips) -> contraction perturbs z by ~1ulp for a ~30-150 walker
// population with rts shifts of the same character (~<=15 steps = 0.15).
// If absmax > threshold: set to 0 to revert (keeps deferred-store win).
#define USE_FMA 1
#if USE_FMA
#define MAD(a, b, c) __fmaf_rn((a), (b), (c))
#else
#define MAD(a, b, c) __fadd_rn(__fmul_rn((a), (b)), (c))
#endif

// Ping-pong survivor lists (i, p-bits), per-round counts, precomputed keys.
__device__ uint2    g_list[2][NWALK];
__device__ uint32_t g_cnt[16];
__device__ uint2    g_keys[NKEYS];

// Threefry-2x32, 20 rounds, exactly JAX's schedule.
__device__ __forceinline__ void tf2x32(uint32_t k0, uint32_t k1,
                                       uint32_t x0, uint32_t x1,
                                       uint32_t& o0, uint32_t& o1) {
  uint32_t ks2 = k0 ^ k1 ^ 0x1BD11BDAu;
  x0 += k0; x1 += k1;
#define TFR(r) { x0 += x1; x1 = (x1 << r) | (x1 >> (32 - r)); x1 ^= x0; }
  TFR(13) TFR(15) TFR(26) TFR(6)
  x0 += k1;  x1 += ks2 + 1u;
  TFR(17) TFR(29) TFR(16) TFR(24)
  x0 += ks2; x1 += k0 + 2u;
  TFR(13) TFR(15) TFR(26) TFR(6)
  x0 += k0;  x1 += k1 + 3u;
  TFR(17) TFR(29) TFR(16) TFR(24)
  x0 += k1;  x1 += ks2 + 4u;
  TFR(13) TFR(15) TFR(26) TFR(6)
  x0 += ks2; x1 += k0 + 5u;
#undef TFR
  o0 = x0; o1 = x1;
}

// init: per-step folded split keys (counter (0,t), key (0,0)) + zero counts.
__global__ void init_kernel() {   // <<<NKEYS/256, 256>>>
  int t = blockIdx.x * 256 + threadIdx.x;
  uint32_t a, b;
  tf2x32(0u, 0u, 0u, (uint32_t)t, a, b);
  g_keys[t] = make_uint2(a, b);
  if (blockIdx.x == 0 && threadIdx.x < 16) g_cnt[threadIdx.x] = 0u;
}

// XLA CPU's log.f32 (Cephes/Eigen-3.3 plog). R8: poly steps contracted to FMA
// (see USE_FMA note). Structure/order unchanged.
__device__ __forceinline__ float xla_cpu_log_f32(float s) {
  uint32_t bits = __float_as_uint(s);
  int emm0 = (int)(bits >> 23) - 0x7f;
  float e = __fadd_rn((float)emm0, 1.0f);
  float m = __uint_as_float((bits & 0x007fffffu) | 0x3f000000u);
  bool mlt = m < 0.70710677f;
  float tmp = mlt ? m : 0.0f;
  float x = __fsub_rn(m, 1.0f);
  e = __fsub_rn(e, mlt ? 1.0f : 0.0f);
  x = __fadd_rn(x, tmp);
  float x2 = __fmul_rn(x, x);
  float x3 = __fmul_rn(x2, x);
  float y, y1, y2;
  y  = MAD(7.0376836292e-2f,  x, -1.1514610310e-1f);
  y1 = MAD(-1.2420140846e-1f, x,  1.4249322787e-1f);
  y2 = MAD(2.0000714765e-1f,  x, -2.4999993993e-1f);
  y  = MAD(y,  x,  1.1676998740e-1f);
  y1 = MAD(y1, x, -1.6668057665e-1f);
  y2 = MAD(y2, x,  3.3333331174e-1f);
  y  = MAD(y, x3, y1);
  y  = MAD(y, x3, y2);
  y  = __fmul_rn(y, x3);
  y  = MAD(e, -2.12194440e-4f, y);
  x  = MAD(x2, -0.5f, x);
  x  = __fadd_rn(x, y);
  x  = MAD(e, 0.693359375f, x);
  return x;
}

// XLA EmitErfInv f32 (Giles): w = -log((1-x)*(1+x)), branch at w<5.
__device__ __forceinline__ float xla_erfinv_f32(float x) {
  float s = __fmul_rn(__fsub_rn(1.0f, x), __fadd_rn(1.0f, x));
  float w = -xla_cpu_log_f32(s);
  float p;
  if (w < 5.0f) {
    float v = __fsub_rn(w, 2.5f);
    p = 2.81022636e-08f;
    p = MAD(p, v, 3.43273939e-07f);
    p = MAD(p, v, -3.5233877e-06f);
    p = MAD(p, v, -4.39150654e-06f);
    p = MAD(p, v, 0.00021858087f);
    p = MAD(p, v, -0.00125372503f);
    p = MAD(p, v, -0.00417768164f);
    p = MAD(p, v, 0.246640727f);
    p = MAD(p, v, 1.50140941f);
  } else {
    float v = __fsub_rn(__fsqrt_rn(w), 3.0f);
    p = -0.000200214257f;
    p = MAD(p, v, 0.000100950558f);
    p = MAD(p, v, 0.00134934322f);
    p = MAD(p, v, -0.00367342844f);
    p = MAD(p, v, 0.00573950773f);
    p = MAD(p, v, -0.0076224613f);
    p = MAD(p, v, 0.00943887047f);
    p = MAD(p, v, 1.00167406f);
    p = MAD(p, v, 2.83297682f);
  }
  return __fmul_rn(p, x);
}

__device__ __forceinline__ float normal_from_bits(uint32_t bits) {
  const float MINVAL = __uint_as_float(0xBF7FFFFFu);   // nextafter(-1,0)
  float f = __uint_as_float((bits >> 9) | 0x3F800000u) - 1.0f;
  float u = MAD(f, 2.0f, MINVAL);
  u = fmaxf(MINVAL, u);
  const float SQRT2 = __uint_as_float(0x3FB504F3u);
  return __fmul_rn(SQRT2, xla_erfinv_f32(u));
}

// Dense round: proven shape (LDS keys, straight 64-step predicated loop, full
// unroll -> cross-step ILP; NO per-step ballots/breaks/barriers). Per-BLOCK
// aggregated atomic. R8: DEFERRED death-store — a lane dies <=once per round,
// so the loop body only records death_s (cndmask-able); the two scattered
// stores + address calc run ONCE post-loop. Shrinks the 64x unrolled body
// (~12 instr/copy of store+addr code) -> less issue + I-cache pressure.
// p freezes at death (alive-guard) so post-loop p is the crossing value.
template<int R>
__device__ __forceinline__
void ddm_round_body(const float* __restrict__ sv_p, const float* __restrict__ rate_p,
                    const float* __restrict__ ndt_p, const float* __restrict__ thr_p,
                    const float* __restrict__ noise_p, const float* __restrict__ dt_p,
                    const int* __restrict__ nw_p, float* __restrict__ out) {
  constexpr int t0 = R * CHUNK;
  int nw = *nw_p;
  uint32_t count = (R == 0) ? (uint32_t)nw : g_cnt[R];
  if (blockIdx.x * BLOCK >= count) return;     // block-uniform: no barriers yet

  __shared__ uint2    skeys[CHUNK];
  __shared__ uint32_t s_woff[BLOCK / 64];
  __shared__ uint32_t s_base;
  if (threadIdx.x < CHUNK) {
    uint32_t a, b;
    tf2x32(0u, 0u, 0u, (uint32_t)(t0 + threadIdx.x), a, b);
    skeys[threadIdx.x] = make_uint2(a, b);
  }
  __syncthreads();

  uint32_t slot = blockIdx.x * BLOCK + threadIdx.x;
  bool alive = slot < count;                   // no wave early-return: barriers below
  float sv = *sv_p, rate = *rate_p, ndt = *ndt_p, thr = *thr_p,
        noise = *noise_p, dt = *dt_p;
  float rate_dt = __fmul_rn(rate, dt);
  float sqrt_dt = __fsqrt_rn(dt);
  int lane = threadIdx.x & 63;
  int wv = threadIdx.x >> 6;

  int i = 0; float p = 0.0f;
  if (alive) {
    if (R == 0) { i = (int)slot; p = __fadd_rn(0.0f, sv); }
    else { uint2 e = g_list[R & 1][slot]; i = (int)e.x; p = __uint_as_float(e.y); }
  }

  int death_s = -1;
  for (int s = 0; s < CHUNK; ++s) {
    if (alive) {                               // dead waves: execz skip, ~free
      uint2 k = skeys[s];                      // uniform s: broadcast, no conflicts
      uint32_t b1, b2;
      tf2x32(k.x, k.y, 0u, (uint32_t)i, b1, b2);
      float z = normal_from_bits(b1 ^ b2);
      p = __fadd_rn(p, __fmul_rn(__fadd_rn(rate_dt, __fmul_rn(noise, z)), sqrt_dt));
      if (!(fabsf(p) < thr)) { death_s = s; alive = false; }
    }
  }
  if (death_s >= 0) {                          // once per dying lane, post-loop
    float rts = (float)(t0 + death_s + 1);     // exact int == accumulated +1.0f
    out[i] = __fadd_rn(ndt, __fmul_rn(rts, dt));
    out[nw + i] = (p <= -thr) ? 0.0f : 1.0f;
  }

  // ---- per-block aggregated compaction: ONE atomic per block ----
  uint64_t m = __ballot(alive);
  if (lane == 0) s_woff[wv] = (uint32_t)__popcll((unsigned long long)m);
  __syncthreads();
  if (threadIdx.x == 0) {
    uint32_t tot = 0;
    #pragma unroll
    for (int w = 0; w < BLOCK / 64; ++w) {
      uint32_t c = s_woff[w]; s_woff[w] = tot; tot += c;   // exclusive prefix
    }
    s_base = tot ? atomicAdd(&g_cnt[R + 1], tot) : 0u;
  }
  __syncthreads();
  if (alive) {
    uint32_t pos = s_base + s_woff[wv] +
                   (uint32_t)__popcll((unsigned long long)(m & ((1ull << lane) - 1ull)));
    g_list[(R + 1) & 1][pos] = make_uint2((uint32_t)i, __float_as_uint(p));
  }
}

// Distinct kernel names per round so rocprof top-k decomposes the timeline.
#define ARGS (const float* __restrict__ sv, const float* __restrict__ rate,   \
              const float* __restrict__ ndt, const float* __restrict__ thr,   \
              const float* __restrict__ noise, const float* __restrict__ dt,  \
              const int* __restrict__ nw, float* __restrict__ out)
#define DEFROUND(NAME, R)                                                     \
  __global__ __launch_bounds__(BLOCK) void NAME ARGS {                        \
    ddm_round_body<R>(sv, rate, ndt, thr, noise, dt, nw, out);                \
  }
DEFROUND(ddm_r0, 0)   DEFROUND(ddm_r1, 1)   DEFROUND(ddm_r2, 2)
DEFROUND(ddm_r3, 3)   DEFROUND(ddm_r4, 4)   DEFROUND(ddm_r5, 5)
#undef DEFROUND
#undef ARGS

// readlane broadcast of a float (forces v_readlane, not ds_bpermute).
__device__ __forceinline__ float rdlane_f(float v, int j) {
  return __uint_as_float((uint32_t)__builtin_amdgcn_readlane((int)__float_as_uint(v), j));
}

// Tail: ONE WALKER PER WAVE. 64 lanes compute q_{t..t+63} in parallel
// (bit-identical op sequence), then a branchless EXACT fold: fully-unrolled
// 64x v_readlane + fadd in strict order, mx tracked per 16-step QUARTER
// (+ p snapshots at quarter boundaries). Death block (~once per walker):
// rescan only the first quarter whose mx >= thr, from its exact snapshot.
// Chain values identical (same adds, same order) -> outputs consistent.
__global__ __launch_bounds__(BLOCK)
void ddm_tail(const float* __restrict__ sv_p, const float* __restrict__ rate_p,
              const float* __restrict__ ndt_p, const float* __restrict__ thr_p,
              const float* __restrict__ noise_p, const float* __restrict__ dt_p,
              const int* __restrict__ nw_p, float* __restrict__ out,
              int round, int t0) {
  int nw = *nw_p;
  float rate = *rate_p, ndt = *ndt_p, thr = *thr_p,
        noise = *noise_p, dt = *dt_p;
  float rate_dt = __fmul_rn(rate, dt);
  float sqrt_dt = __fsqrt_rn(dt);

  int lane = threadIdx.x & 63;
  uint32_t wave = blockIdx.x * (BLOCK / 64) + (threadIdx.x >> 6);
  uint32_t nwaves = gridDim.x * (BLOCK / 64);
  uint32_t count = g_cnt[round];

  for (uint32_t k = wave; k < count; k += nwaves) {
    uint2 e = g_list[round & 1][k];
    int i = (int)e.x;
    float p = __uint_as_float(e.y);        // wave-uniform from here on
    int t = t0;
    int rts_i = NSTEPS;
    bool done = false;
    while (!done) {
      int valid = NSTEPS - t; if (valid > 64) valid = 64;
      int tl = t + (lane < valid ? lane : valid - 1);
      uint2 kk = g_keys[tl];               // coalesced 8B, L2-resident
      uint32_t b1, b2;
      tf2x32(kk.x, kk.y, 0u, (uint32_t)i, b1, b2);
      float z = normal_from_bits(b1 ^ b2);
      float q = __fmul_rn(__fadd_rn(rate_dt, __fmul_rn(noise, z)), sqrt_dt);

      if (valid == 64) {
        // ---- branchless exact fold, quarter-snapshotted ----
        float s0 = p, mx0 = 0.0f, mx1 = 0.0f, mx2 = 0.0f, mx3 = 0.0f;
        #pragma unroll
        for (int j = 0; j < 16; ++j) {
          p = __fadd_rn(p, rdlane_f(q, j));  mx0 = fmaxf(mx0, fabsf(p));
        }
        float s1 = p;
        #pragma unroll
        for (int j = 16; j < 32; ++j) {
          p = __fadd_rn(p, rdlane_f(q, j));  mx1 = fmaxf(mx1, fabsf(p));
        }
        float s2 = p;
        #pragma unroll
        for (int j = 32; j < 48; ++j) {
          p = __fadd_rn(p, rdlane_f(q, j));  mx2 = fmaxf(mx2, fabsf(p));
        }
        float s3 = p;
        #pragma unroll
        for (int j = 48; j < 64; ++j) {
          p = __fadd_rn(p, rdlane_f(q, j));  mx3 = fmaxf(mx3, fabsf(p));
        }
        if (fmaxf(fmaxf(mx0, mx1), fmaxf(mx2, mx3)) >= thr) {
          // death block: first crossing lives in the FIRST quarter w/ mx>=thr
          float pr; int jb;
          if      (mx0 >= thr) { pr = s0; jb = 0;  }
          else if (mx1 >= thr) { pr = s1; jb = 16; }
          else if (mx2 >= thr) { pr = s2; jb = 32; }
          else                 { pr = s3; jb = 48; }
          for (int j = 0; j < 16; ++j) {   // exact re-scan from snapshot
            pr = __fadd_rn(pr, rdlane_f(q, jb + j));
            if (!(fabsf(pr) < thr)) {
              rts_i = t + jb + j + 1; p = pr; done = true; break;
            }
          }
        } else {
          t += 64;
          if (t >= NSTEPS) done = true;    // ran out the clock: rts = 3000
        }
      } else {
        // rare partial final block: original checked scan
        for (int j = 0; j < valid; ++j) {
          float qj = rdlane_f(q, j);
          p = __fadd_rn(p, qj);
          if (!(fabsf(p) < thr)) { rts_i = t + j + 1; done = true; break; }
        }
        if (!done) {
          t += valid;
          if (t >= NSTEPS) done = true;
        }
      }
    }
    if (lane == 0) {
      out[i] = __fadd_rn(ndt, __fmul_rn((float)rts_i, dt));
      out[nw + i] = (p <= -thr) ? 0.0f : 1.0f;
    }
  }
}

extern "C" void kernel_launch(void* const* d_in, const int* in_sizes, int n_in,
                              void* d_out, int out_size, void* d_ws, size_t ws_size,
                              hipStream_t stream) {
  const float* sv    = (const float*)d_in[0];
  const float* rate  = (const float*)d_in[1];
  const float* ndt   = (const float*)d_in[2];
  const float* thr   = (const float*)d_in[3];
  const float* noise = (const float*)d_in[4];
  const float* dt    = (const float*)d_in[5];
  const int*   nw    = (const int*)d_in[6];
  float* out = (float*)d_out;

  init_kernel<<<NKEYS / 256, 256, 0, stream>>>();
  ddm_r0<<<NBD, BLOCK, 0, stream>>>(sv, rate, ndt, thr, noise, dt, nw, out);
  ddm_r1<<<NBD, BLOCK, 0, stream>>>(sv, rate, ndt, thr, noise, dt, nw, out);
  ddm_r2<<<NBD, BLOCK, 0, stream>>>(sv, rate, ndt, thr, noise, dt, nw, out);
  ddm_r3<<<NBD, BLOCK, 0, stream>>>(sv, rate, ndt, thr, noise, dt, nw, out);
  ddm_r4<<<NBD, BLOCK, 0, stream>>>(sv, rate, ndt, thr, noise, dt, nw, out);
  ddm_r5<<<NBD, BLOCK, 0, stream>>>(sv, rate, ndt, thr, noise, dt, nw, out);
  ddm_tail<<<NBT, BLOCK, 0, stream>>>(sv, rate, ndt, thr, noise, dt, nw, out,
                                      NDENSE, NDENSE * CHUNK);
}

// Round 9
// 521.702 us; speedup vs baseline: 1.9687x; 1.0175x over previous
//
#include <hip/hip_runtime.h>
#include <math.h>

#define NSTEPS 3000
#define NWALK  1048576
#define BLOCK  256
#define NBD    (NWALK / BLOCK)   // 4096 dense blocks: one slot per lane
#define NDENSE 6                 // dense rounds cover t in [0, 384), 64 steps each
#define CHUNK  64
#define NBT    4096              // tail grid: 16384 waves
#define NKEYS  3072

// FMA contraction (R8: passed, absmax identical 0.09375 — zero flips).
#define MAD(a, b, c) __fmaf_rn((a), (b), (c))

// Ping-pong survivor lists (i, p-bits), per-round counts, precomputed keys.
__device__ uint2    g_list[2][NWALK];
__device__ uint32_t g_cnt[16];
__device__ uint2    g_keys[NKEYS];

// Threefry-2x32, 20 rounds, exactly JAX's schedule.
__device__ __forceinline__ void tf2x32(uint32_t k0, uint32_t k1,
                                       uint32_t x0, uint32_t x1,
                                       uint32_t& o0, uint32_t& o1) {
  uint32_t ks2 = k0 ^ k1 ^ 0x1BD11BDAu;
  x0 += k0; x1 += k1;
#define TFR(r) { x0 += x1; x1 = (x1 << r) | (x1 >> (32 - r)); x1 ^= x0; }
  TFR(13) TFR(15) TFR(26) TFR(6)
  x0 += k1;  x1 += ks2 + 1u;
  TFR(17) TFR(29) TFR(16) TFR(24)
  x0 += ks2; x1 += k0 + 2u;
  TFR(13) TFR(15) TFR(26) TFR(6)
  x0 += k0;  x1 += k1 + 3u;
  TFR(17) TFR(29) TFR(16) TFR(24)
  x0 += k1;  x1 += ks2 + 4u;
  TFR(13) TFR(15) TFR(26) TFR(6)
  x0 += ks2; x1 += k0 + 5u;
#undef TFR
  o0 = x0; o1 = x1;
}

// init: per-step folded split keys (counter (0,t), key (0,0)) + zero counts.
__global__ void init_kernel() {   // <<<NKEYS/256, 256>>>
  int t = blockIdx.x * 256 + threadIdx.x;
  uint32_t a, b;
  tf2x32(0u, 0u, 0u, (uint32_t)t, a, b);
  g_keys[t] = make_uint2(a, b);
  if (blockIdx.x == 0 && threadIdx.x < 16) g_cnt[threadIdx.x] = 0u;
}

// XLA CPU's log.f32 (Cephes/Eigen-3.3 plog), FMA-contracted (R8-verified).
__device__ __forceinline__ float xla_cpu_log_f32(float s) {
  uint32_t bits = __float_as_uint(s);
  int emm0 = (int)(bits >> 23) - 0x7f;
  float e = __fadd_rn((float)emm0, 1.0f);
  float m = __uint_as_float((bits & 0x007fffffu) | 0x3f000000u);
  bool mlt = m < 0.70710677f;
  float tmp = mlt ? m : 0.0f;
  float x = __fsub_rn(m, 1.0f);
  e = __fsub_rn(e, mlt ? 1.0f : 0.0f);
  x = __fadd_rn(x, tmp);
  float x2 = __fmul_rn(x, x);
  float x3 = __fmul_rn(x2, x);
  float y, y1, y2;
  y  = MAD(7.0376836292e-2f,  x, -1.1514610310e-1f);
  y1 = MAD(-1.2420140846e-1f, x,  1.4249322787e-1f);
  y2 = MAD(2.0000714765e-1f,  x, -2.4999993993e-1f);
  y  = MAD(y,  x,  1.1676998740e-1f);
  y1 = MAD(y1, x, -1.6668057665e-1f);
  y2 = MAD(y2, x,  3.3333331174e-1f);
  y  = MAD(y, x3, y1);
  y  = MAD(y, x3, y2);
  y  = __fmul_rn(y, x3);
  y  = MAD(e, -2.12194440e-4f, y);
  x  = MAD(x2, -0.5f, x);
  x  = __fadd_rn(x, y);
  x  = MAD(e, 0.693359375f, x);
  return x;
}

// XLA EmitErfInv f32 (Giles): w = -log((1-x)*(1+x)), branch at w<5.
__device__ __forceinline__ float xla_erfinv_f32(float x) {
  float s = __fmul_rn(__fsub_rn(1.0f, x), __fadd_rn(1.0f, x));
  float w = -xla_cpu_log_f32(s);
  float p;
  if (w < 5.0f) {
    float v = __fsub_rn(w, 2.5f);
    p = 2.81022636e-08f;
    p = MAD(p, v, 3.43273939e-07f);
    p = MAD(p, v, -3.5233877e-06f);
    p = MAD(p, v, -4.39150654e-06f);
    p = MAD(p, v, 0.00021858087f);
    p = MAD(p, v, -0.00125372503f);
    p = MAD(p, v, -0.00417768164f);
    p = MAD(p, v, 0.246640727f);
    p = MAD(p, v, 1.50140941f);
  } else {
    float v = __fsub_rn(__fsqrt_rn(w), 3.0f);
    p = -0.000200214257f;
    p = MAD(p, v, 0.000100950558f);
    p = MAD(p, v, 0.00134934322f);
    p = MAD(p, v, -0.00367342844f);
    p = MAD(p, v, 0.00573950773f);
    p = MAD(p, v, -0.0076224613f);
    p = MAD(p, v, 0.00943887047f);
    p = MAD(p, v, 1.00167406f);
    p = MAD(p, v, 2.83297682f);
  }
  return __fmul_rn(p, x);
}

__device__ __forceinline__ float normal_from_bits(uint32_t bits) {
  const float MINVAL = __uint_as_float(0xBF7FFFFFu);   // nextafter(-1,0)
  float f = __uint_as_float((bits >> 9) | 0x3F800000u) - 1.0f;
  float u = MAD(f, 2.0f, MINVAL);
  u = fmaxf(MINVAL, u);
  const float SQRT2 = __uint_as_float(0x3FB504F3u);
  return __fmul_rn(SQRT2, xla_erfinv_f32(u));
}

// Dense round: proven per-step shape (LDS-key broadcast, predicated body, NO
// per-step ballots/breaks/barriers), per-BLOCK aggregated atomic, deferred
// death-store (R8). R9: PARTIAL UNROLL 4x16 — the 64x body was ~77KB of
// straight-line code vs 32KB L1I (fetch-stall suspect: VALU-slot model says
// 132us, measured 197us). 16-step body ~19KB fits L1I; outer loop kept
// runtime (unroll-disabled) so code size stays bounded. Inner 16 steps give
// ample cross-step ILP (independent threefry chains); TLP covers the rest.
template<int R>
__device__ __forceinline__
void ddm_round_body(const float* __restrict__ sv_p, const float* __restrict__ rate_p,
                    const float* __restrict__ ndt_p, const float* __restrict__ thr_p,
                    const float* __restrict__ noise_p, const float* __restrict__ dt_p,
                    const int* __restrict__ nw_p, float* __restrict__ out) {
  constexpr int t0 = R * CHUNK;
  int nw = *nw_p;
  uint32_t count = (R == 0) ? (uint32_t)nw : g_cnt[R];
  if (blockIdx.x * BLOCK >= count) return;     // block-uniform: no barriers yet

  __shared__ uint2    skeys[CHUNK];
  __shared__ uint32_t s_woff[BLOCK / 64];
  __shared__ uint32_t s_base;
  if (threadIdx.x < CHUNK) {
    uint32_t a, b;
    tf2x32(0u, 0u, 0u, (uint32_t)(t0 + threadIdx.x), a, b);
    skeys[threadIdx.x] = make_uint2(a, b);
  }
  __syncthreads();

  uint32_t slot = blockIdx.x * BLOCK + threadIdx.x;
  bool alive = slot < count;                   // no wave early-return: barriers below
  float sv = *sv_p, rate = *rate_p, ndt = *ndt_p, thr = *thr_p,
        noise = *noise_p, dt = *dt_p;
  float rate_dt = __fmul_rn(rate, dt);
  float sqrt_dt = __fsqrt_rn(dt);
  int lane = threadIdx.x & 63;
  int wv = threadIdx.x >> 6;

  int i = 0; float p = 0.0f;
  if (alive) {
    if (R == 0) { i = (int)slot; p = __fadd_rn(0.0f, sv); }
    else { uint2 e = g_list[R & 1][slot]; i = (int)e.x; p = __uint_as_float(e.y); }
  }

  int death_s = -1;
  #pragma clang loop unroll(disable)
  for (int c = 0; c < CHUNK / 16; ++c) {       // runtime outer: code stays 16-step
    #pragma unroll
    for (int j = 0; j < 16; ++j) {
      int s = c * 16 + j;
      if (alive) {                             // dead waves: execz skip, ~free
        uint2 k = skeys[s];                    // uniform s: broadcast, no conflicts
        uint32_t b1, b2;
        tf2x32(k.x, k.y, 0u, (uint32_t)i, b1, b2);
        float z = normal_from_bits(b1 ^ b2);
        p = __fadd_rn(p, __fmul_rn(__fadd_rn(rate_dt, __fmul_rn(noise, z)), sqrt_dt));
        if (!(fabsf(p) < thr)) { death_s = s; alive = false; }
      }
    }
  }
  if (death_s >= 0) {                          // once per dying lane, post-loop
    float rts = (float)(t0 + death_s + 1);     // exact int == accumulated +1.0f
    out[i] = __fadd_rn(ndt, __fmul_rn(rts, dt));
    out[nw + i] = (p <= -thr) ? 0.0f : 1.0f;
  }

  // ---- per-block aggregated compaction: ONE atomic per block ----
  uint64_t m = __ballot(alive);
  if (lane == 0) s_woff[wv] = (uint32_t)__popcll((unsigned long long)m);
  __syncthreads();
  if (threadIdx.x == 0) {
    uint32_t tot = 0;
    #pragma unroll
    for (int w = 0; w < BLOCK / 64; ++w) {
      uint32_t c = s_woff[w]; s_woff[w] = tot; tot += c;   // exclusive prefix
    }
    s_base = tot ? atomicAdd(&g_cnt[R + 1], tot) : 0u;
  }
  __syncthreads();
  if (alive) {
    uint32_t pos = s_base + s_woff[wv] +
                   (uint32_t)__popcll((unsigned long long)(m & ((1ull << lane) - 1ull)));
    g_list[(R + 1) & 1][pos] = make_uint2((uint32_t)i, __float_as_uint(p));
  }
}

// Distinct kernel names per round so rocprof top-k decomposes the timeline.
#define ARGS (const float* __restrict__ sv, const float* __restrict__ rate,   \
              const float* __restrict__ ndt, const float* __restrict__ thr,   \
              const float* __restrict__ noise, const float* __restrict__ dt,  \
              const int* __restrict__ nw, float* __restrict__ out)
#define DEFROUND(NAME, R)                                                     \
  __global__ __launch_bounds__(BLOCK) void NAME ARGS {                        \
    ddm_round_body<R>(sv, rate, ndt, thr, noise, dt, nw, out);                \
  }
DEFROUND(ddm_r0, 0)   DEFROUND(ddm_r1, 1)   DEFROUND(ddm_r2, 2)
DEFROUND(ddm_r3, 3)   DEFROUND(ddm_r4, 4)   DEFROUND(ddm_r5, 5)
#undef DEFROUND
#undef ARGS

// readlane broadcast of a float (forces v_readlane, not ds_bpermute).
__device__ __forceinline__ float rdlane_f(float v, int j) {
  return __uint_as_float((uint32_t)__builtin_amdgcn_readlane((int)__float_as_uint(v), j));
}

// Tail: ONE WALKER PER WAVE. 64 lanes compute q_{t..t+63} in parallel
// (bit-identical op sequence), then a branchless EXACT fold: fully-unrolled
// 64x v_readlane + fadd in strict order, mx tracked per 16-step QUARTER
// (+ p snapshots at quarter boundaries). Death block (~once per walker):
// rescan only the first quarter whose mx >= thr, from its exact snapshot.
// Body ~3KB — already fits L1I; unchanged.
__global__ __launch_bounds__(BLOCK)
void ddm_tail(const float* __restrict__ sv_p, const float* __restrict__ rate_p,
              const float* __restrict__ ndt_p, const float* __restrict__ thr_p,
              const float* __restrict__ noise_p, const float* __restrict__ dt_p,
              const int* __restrict__ nw_p, float* __restrict__ out,
              int round, int t0) {
  int nw = *nw_p;
  float rate = *rate_p, ndt = *ndt_p, thr = *thr_p,
        noise = *noise_p, dt = *dt_p;
  float rate_dt = __fmul_rn(rate, dt);
  float sqrt_dt = __fsqrt_rn(dt);

  int lane = threadIdx.x & 63;
  uint32_t wave = blockIdx.x * (BLOCK / 64) + (threadIdx.x >> 6);
  uint32_t nwaves = gridDim.x * (BLOCK / 64);
  uint32_t count = g_cnt[round];

  for (uint32_t k = wave; k < count; k += nwaves) {
    uint2 e = g_list[round & 1][k];
    int i = (int)e.x;
    float p = __uint_as_float(e.y);        // wave-uniform from here on
    int t = t0;
    int rts_i = NSTEPS;
    bool done = false;
    while (!done) {
      int valid = NSTEPS - t; if (valid > 64) valid = 64;
      int tl = t + (lane < valid ? lane : valid - 1);
      uint2 kk = g_keys[tl];               // coalesced 8B, L2-resident
      uint32_t b1, b2;
      tf2x32(kk.x, kk.y, 0u, (uint32_t)i, b1, b2);
      float z = normal_from_bits(b1 ^ b2);
      float q = __fmul_rn(__fadd_rn(rate_dt, __fmul_rn(noise, z)), sqrt_dt);

      if (valid == 64) {
        // ---- branchless exact fold, quarter-snapshotted ----
        float s0 = p, mx0 = 0.0f, mx1 = 0.0f, mx2 = 0.0f, mx3 = 0.0f;
        #pragma unroll
        for (int j = 0; j < 16; ++j) {
          p = __fadd_rn(p, rdlane_f(q, j));  mx0 = fmaxf(mx0, fabsf(p));
        }
        float s1 = p;
        #pragma unroll
        for (int j = 16; j < 32; ++j) {
          p = __fadd_rn(p, rdlane_f(q, j));  mx1 = fmaxf(mx1, fabsf(p));
        }
        float s2 = p;
        #pragma unroll
        for (int j = 32; j < 48; ++j) {
          p = __fadd_rn(p, rdlane_f(q, j));  mx2 = fmaxf(mx2, fabsf(p));
        }
        float s3 = p;
        #pragma unroll
        for (int j = 48; j < 64; ++j) {
          p = __fadd_rn(p, rdlane_f(q, j));  mx3 = fmaxf(mx3, fabsf(p));
        }
        if (fmaxf(fmaxf(mx0, mx1), fmaxf(mx2, mx3)) >= thr) {
          // death block: first crossing lives in the FIRST quarter w/ mx>=thr
          float pr; int jb;
          if      (mx0 >= thr) { pr = s0; jb = 0;  }
          else if (mx1 >= thr) { pr = s1; jb = 16; }
          else if (mx2 >= thr) { pr = s2; jb = 32; }
          else                 { pr = s3; jb = 48; }
          for (int j = 0; j < 16; ++j) {   // exact re-scan from snapshot
            pr = __fadd_rn(pr, rdlane_f(q, jb + j));
            if (!(fabsf(pr) < thr)) {
              rts_i = t + jb + j + 1; p = pr; done = true; break;
            }
          }
        } else {
          t += 64;
          if (t >= NSTEPS) done = true;    // ran out the clock: rts = 3000
        }
      } else {
        // rare partial final block: original checked scan
        for (int j = 0; j < valid; ++j) {
          float qj = rdlane_f(q, j);
          p = __fadd_rn(p, qj);
          if (!(fabsf(p) < thr)) { rts_i = t + j + 1; done = true; break; }
        }
        if (!done) {
          t += valid;
          if (t >= NSTEPS) done = true;
        }
      }
    }
    if (lane == 0) {
      out[i] = __fadd_rn(ndt, __fmul_rn((float)rts_i, dt));
      out[nw + i] = (p <= -thr) ? 0.0f : 1.0f;
    }
  }
}

extern "C" void kernel_launch(void* const* d_in, const int* in_sizes, int n_in,
                              void* d_out, int out_size, void* d_ws, size_t ws_size,
                              hipStream_t stream) {
  const float* sv    = (const float*)d_in[0];
  const float* rate  = (const float*)d_in[1];
  const float* ndt   = (const float*)d_in[2];
  const float* thr   = (const float*)d_in[3];
  const float* noise = (const float*)d_in[4];
  const float* dt    = (const float*)d_in[5];
  const int*   nw    = (const int*)d_in[6];
  float* out = (float*)d_out;

  init_kernel<<<NKEYS / 256, 256, 0, stream>>>();
  ddm_r0<<<NBD, BLOCK, 0, stream>>>(sv, rate, ndt, thr, noise, dt, nw, out);
  ddm_r1<<<NBD, BLOCK, 0, stream>>>(sv, rate, ndt, thr, noise, dt, nw, out);
  ddm_r2<<<NBD, BLOCK, 0, stream>>>(sv, rate, ndt, thr, noise, dt, nw, out);
  ddm_r3<<<NBD, BLOCK, 0, stream>>>(sv, rate, ndt, thr, noise, dt, nw, out);
  ddm_r4<<<NBD, BLOCK, 0, stream>>>(sv, rate, ndt, thr, noise, dt, nw, out);
  ddm_r5<<<NBD, BLOCK, 0, stream>>>(sv, rate, ndt, thr, noise, dt, nw, out);
  ddm_tail<<<NBT, BLOCK, 0, stream>>>(sv, rate, ndt, thr, noise, dt, nw, out,
                                      NDENSE, NDENSE * CHUNK);
}